// Round 6
// baseline (270.305 us; speedup 1.0000x reference)
//
#include <hip/hip_runtime.h>
#include <math.h>

#define TPB 256
#define KTOP 10
#define GMAX 32
#define NSEG 8
#define SEGIT 5   // ceil(ceil(8400/NSEG)/TPB) = ceil(1050/256) = 5

__device__ __forceinline__ bool read_maskgt(const void* p, int i) {
    const unsigned char* b = (const unsigned char*)p;
    // counts >= 8 so mask_gt[0][1] is always true: byte[1]!=0 <=> bool-byte layout.
    if (b[1] != 0) return b[i] != 0;
    // int32 (value 0/1) or float32 (bits of 0.0/1.0) both: nonzero word == true
    return ((const int*)p)[i] != 0;
}

// lexicographic (value, min idx) argmin/argmax across the 64-lane wave;
// shfl_xor butterfly -> every lane ends with the global winner.
__device__ __forceinline__ void wave_argmin(float& v, int& i) {
    for (int off = 32; off; off >>= 1) {
        float ov = __shfl_xor(v, off);
        int   oi = __shfl_xor(i, off);
        if (ov < v || (ov == v && oi < i)) { v = ov; i = oi; }
    }
}
__device__ __forceinline__ void wave_argmax(float& v, int& i) {
    for (int off = 32; off; off >>= 1) {
        float ov = __shfl_xor(v, off);
        int   oi = __shfl_xor(i, off);
        if (ov > v || (ov == v && oi < i)) { v = ov; i = oi; }
    }
}

// ---------------- K0: zero outputs + num_pts accumulators ----------------
__global__ void k0_init(float* out, int* numpts, int bs) {
    int t = threadIdx.x;
    if (t < 3) out[t] = 0.0f;
    if (t < bs) numpts[t] = 0;
}

// ---------------- K1: per-(b,a) class sums S, Se ----------------
__global__ void k1_scores(const float* __restrict__ ps, float* __restrict__ S,
                          float* __restrict__ Se, int rows, int NC) {
    int r = blockIdx.x * 4 + (threadIdx.x >> 6);
    int lane = threadIdx.x & 63;
    if (r >= rows) return;
    const float* row = ps + (long)r * NC;
    float s = 0.f, se = 0.f;
    for (int c = lane; c < NC; c += 64) {
        float p = row[c];
        s  += -fmaxf(logf(1.0f - p), -100.0f);
        se += -logf(1.0f - p + 1e-7f);
    }
    for (int off = 32; off; off >>= 1) {
        s  += __shfl_down(s, off);
        se += __shfl_down(se, off);
    }
    if (lane == 0) { S[r] = s; Se[r] = se; }
}

// ---------------- K2a: fused cost over all g per anchor (row-local gather) ----
__global__ void k2a_cost(const float* __restrict__ pred_boxes,
                         const float* __restrict__ gt_boxes,
                         const void*  mask_gt,
                         const float* __restrict__ ps,
                         const int*   __restrict__ labels,
                         const float* __restrict__ anchors,
                         const float* __restrict__ strides,
                         const float* __restrict__ S,
                         float* __restrict__ cost,
                         unsigned char* __restrict__ mask,
                         unsigned char* __restrict__ best,
                         int G, int HW, int NC) {
    __shared__ float4 s_gb[GMAX];
    __shared__ float  s_ctrx[GMAX], s_ctry[GMAX];
    __shared__ int    s_lab[GMAX];
    __shared__ int    s_val[GMAX];

    int b = blockIdx.y;
    int tid = threadIdx.x;
    if (tid < G) {
        int pr = b * G + tid;
        float4 gb = ((const float4*)gt_boxes)[pr];
        s_gb[tid] = gb;
        s_ctrx[tid] = (gb.x + gb.z) * 0.5f;
        s_ctry[tid] = (gb.y + gb.w) * 0.5f;
        s_lab[tid] = labels[pr];
        s_val[tid] = read_maskgt(mask_gt, pr) ? 1 : 0;
    }
    __syncthreads();

    int a = blockIdx.x * TPB + tid;
    if (a >= HW) return;

    const float4 pb = ((const float4*)(pred_boxes + (long)b * HW * 4))[a];
    float ax = anchors[2 * a], ay = anchors[2 * a + 1];
    float st = strides[a];
    float apx = (ax + 0.5f) * st, apy = (ay + 0.5f) * st;
    float dis = 2.5f * st;
    float Sa = S[(long)b * HW + a];
    float w1 = pb.z - pb.x, h1 = pb.w - pb.y + 1e-9f;
    float w1h1 = w1 * h1;
    const float* __restrict__ row = ps + ((long)b * HW + a) * NC;

    float bestc = 3.4e38f;
    int bestg = 0;

#pragma unroll
    for (int g = 0; g < GMAX; ++g) {
        if (g >= G) break;
        long oidx = ((long)(b * G + g)) * HW + a;
        float c;
        if (!s_val[g]) {
            c = 1e6f;
        } else {
            float pl = row[s_lab[g]];
            float4 gb = s_gb[g];
            float gx1 = gb.x, gy1 = gb.y, gx2 = gb.z, gy2 = gb.w;
            bool in_boxes = (apx - gx1 > 0.f) & (apy - gy1 > 0.f) &
                            (gx2 - apx > 0.f) & (gy2 - apy > 0.f);
            float ctrx = s_ctrx[g], ctry = s_ctry[g];
            bool in_centers = (apx - (ctrx - dis) > 0.f) & (apy - (ctry - dis) > 0.f) &
                              ((ctrx + dis) - apx > 0.f) & ((ctry + dis) - apy > 0.f);
            bool fg = in_boxes | in_centers;
            bool in_both = in_boxes & in_centers;

            float w2 = gx2 - gx1, h2 = gy2 - gy1 + 1e-9f;
            float iw = fminf(pb.z, gx2) - fmaxf(pb.x, gx1);
            float ih = fminf(pb.w, gy2) - fmaxf(pb.y, gy1);
            float inter = fmaxf(iw, 0.f) * fmaxf(ih, 0.f);
            float uni = w1h1 + w2 * h2 - inter + 1e-9f;
            float iou = inter / uni;
            float iou_cost = -logf(iou + 1e-7f);

            float nll0 = -fmaxf(logf(pl), -100.f);
            float nll1 = -fmaxf(logf(1.f - pl), -100.f);
            float cls = Sa + (fg ? (nll0 - nll1) : 0.f);
            c = cls + 3.f * iou_cost + (in_both ? 0.f : 100000.f);
        }
        cost[oidx] = c;
        mask[oidx] = 0;
        if (c < bestc) { bestc = c; bestg = g; }   // first occurrence wins
    }
    best[(long)b * HW + a] = (unsigned char)bestg;
}

// ---------------- K2b1: per-(pair,segment) top-10 candidates ----------------
// grid (BS*G, NSEG). Each block scans ~1050 anchors; each thread keeps its <=5
// candidates in statically-indexed registers; 10-round shfl_xor lexicographic
// extraction per wave; tiny LDS hop; final 40-cand merge by wave 0.
__global__ void k2b1_seg(const float* __restrict__ pred_boxes,
                         const float* __restrict__ gt_boxes,
                         const void*  mask_gt,
                         const float* __restrict__ anchors,
                         const float* __restrict__ strides,
                         const float* __restrict__ cost,
                         float* __restrict__ cand_c,
                         int*   __restrict__ cand_i,
                         float* __restrict__ cand_v,
                         int*   __restrict__ cand_vi,
                         int G, int HW) {
    int pair = blockIdx.x;
    int seg  = blockIdx.y;
    if (!read_maskgt(mask_gt, pair)) return;

    int b = pair / G;
    int tid = threadIdx.x;
    int lane = tid & 63;
    int wid = tid >> 6;

    int seglen = (HW + NSEG - 1) / NSEG;
    int a0 = seg * seglen;
    int a1 = min(a0 + seglen, HW);

    const float4 gb = ((const float4*)gt_boxes)[pair];
    const float gx1 = gb.x, gy1 = gb.y, gx2 = gb.z, gy2 = gb.w;
    const float ctrx = (gx1 + gx2) * 0.5f, ctry = (gy1 + gy2) * 0.5f;
    const float w2 = gx2 - gx1, h2 = gy2 - gy1 + 1e-9f;

    const float* pbb  = pred_boxes + (long)b * HW * 4;
    const float* crow = cost + (long)pair * HW;

    float cv[SEGIT]; int ci[SEGIT]; float iv[SEGIT];
#pragma unroll
    for (int it = 0; it < SEGIT; ++it) {
        int a = a0 + tid + it * TPB;
        bool ok = a < a1;
        float c = 3e38f, ivl = -3e38f;
        int idx = 0x7fffffff;
        if (ok) {
            float4 pb = ((const float4*)pbb)[a];
            float ax = anchors[2 * a], ay = anchors[2 * a + 1];
            float st = strides[a];
            float apx = (ax + 0.5f) * st, apy = (ay + 0.5f) * st;
            bool in_boxes = (apx - gx1 > 0.f) & (apy - gy1 > 0.f) &
                            (gx2 - apx > 0.f) & (gy2 - apy > 0.f);
            float dis = 2.5f * st;
            bool in_centers = (apx - (ctrx - dis) > 0.f) & (apy - (ctry - dis) > 0.f) &
                              ((ctrx + dis) - apx > 0.f) & ((ctry + dis) - apy > 0.f);
            bool fg = in_boxes | in_centers;

            float w1 = pb.z - pb.x, h1 = pb.w - pb.y + 1e-9f;
            float w1h1 = w1 * h1;
            float iw = fminf(pb.z, gx2) - fmaxf(pb.x, gx1);
            float ih = fminf(pb.w, gy2) - fmaxf(pb.y, gy1);
            float inter = fmaxf(iw, 0.f) * fmaxf(ih, 0.f);
            float uni = w1h1 + w2 * h2 - inter + 1e-9f;
            float iou = inter / uni;

            c = crow[a];
            idx = a;
            ivl = fg ? iou : -3e38f;
        }
        cv[it] = c; ci[it] = idx; iv[it] = ivl;
    }

    // ---- per-wave top-10 extraction (registers + shfl only) ----
    float myc = 3e38f;  int myi = 0x7fffffff;
    float myv = -3e38f; int myvi = 0x7fffffff;
#pragma unroll
    for (int r = 0; r < KTOP; ++r) {
        // cost argmin
        float v = cv[0]; int i = ci[0];
#pragma unroll
        for (int j = 1; j < SEGIT; ++j)
            if (cv[j] < v || (cv[j] == v && ci[j] < i)) { v = cv[j]; i = ci[j]; }
        wave_argmin(v, i);
        if (lane == r) { myc = v; myi = i; }
#pragma unroll
        for (int j = 0; j < SEGIT; ++j) if (ci[j] == i) cv[j] = 3e38f;
        // iou argmax
        float u = iv[0]; int ui = ci[0];
#pragma unroll
        for (int j = 1; j < SEGIT; ++j)
            if (iv[j] > u || (iv[j] == u && ci[j] < ui)) { u = iv[j]; ui = ci[j]; }
        wave_argmax(u, ui);
        if (lane == r) { myv = u; myvi = ui; }
#pragma unroll
        for (int j = 0; j < SEGIT; ++j) if (ci[j] == ui) iv[j] = -3e38f;
    }

    __shared__ float s_c[4][KTOP];  __shared__ int s_i[4][KTOP];
    __shared__ float s_v[4][KTOP];  __shared__ int s_vi[4][KTOP];
    if (lane < KTOP) {
        s_c[wid][lane] = myc;  s_i[wid][lane] = myi;
        s_v[wid][lane] = myv;  s_vi[wid][lane] = myvi;
    }
    __syncthreads();

    if (wid == 0) {
        float c40 = 3e38f;  int i40 = 0x7fffffff;
        float v40 = -3e38f; int vi40 = 0x7fffffff;
        if (lane < 4 * KTOP) {
            c40 = s_c[lane / KTOP][lane % KTOP];
            i40 = s_i[lane / KTOP][lane % KTOP];
            v40 = s_v[lane / KTOP][lane % KTOP];
            vi40 = s_vi[lane / KTOP][lane % KTOP];
        }
        float fc = 3e38f;  int fi = 0x7fffffff;
        float fv = -3e38f; int fvi = 0x7fffffff;
#pragma unroll
        for (int r = 0; r < KTOP; ++r) {
            float v = c40; int i = i40;
            wave_argmin(v, i);
            if (lane == r) { fc = v; fi = i; }
            if (i40 == i) c40 = 3e38f;
            float u = v40; int ui = vi40;
            wave_argmax(u, ui);
            if (lane == r) { fv = u; fvi = ui; }
            if (vi40 == ui) v40 = -3e38f;
        }
        long obase = ((long)pair * NSEG + seg) * KTOP;
        if (lane < KTOP) {
            cand_c[obase + lane] = fc;   cand_i[obase + lane] = fi;
            cand_v[obase + lane] = fv;   cand_vi[obase + lane] = fvi;
        }
    }
}

// ---------------- K2b2: merge 8x10 candidates per pair, set mask ----------------
// grid BS*G, one wave per pair.
__global__ void k2b2_merge(const void* mask_gt,
                           const float* __restrict__ cand_c,
                           const int*   __restrict__ cand_i,
                           const float* __restrict__ cand_v,
                           const int*   __restrict__ cand_vi,
                           unsigned char* __restrict__ mask,
                           int HW) {
    int pair = blockIdx.x;
    if (!read_maskgt(mask_gt, pair)) return;
    int t = threadIdx.x;   // 0..63

    long base = (long)pair * NSEG * KTOP;   // 80 candidates
    float c0 = cand_c[base + t];
    int   i0 = cand_i[base + t];
    float v0 = cand_v[base + t];
    int   vi0 = cand_vi[base + t];
    float c1 = 3e38f;  int i1 = 0x7fffffff;
    float v1 = -3e38f; int vi1 = 0x7fffffff;
    if (t < NSEG * KTOP - 64) {
        c1 = cand_c[base + 64 + t];   i1 = cand_i[base + 64 + t];
        v1 = cand_v[base + 64 + t];   vi1 = cand_vi[base + 64 + t];
    }

    // pt_num: sum of 10 largest fg-ious, descending order (matches top_k+sum)
    float ptsum = 0.f;
#pragma unroll
    for (int r = 0; r < KTOP; ++r) {
        float u = v0; int ui = vi0;
        if (v1 > u || (v1 == u && vi1 < ui)) { u = v1; ui = vi1; }
        wave_argmax(u, ui);
        ptsum += fmaxf(u, 0.f);   // -3e38 sentinel -> 0 (isfinite semantics)
        if (vi0 == ui) v0 = -3e38f;
        if (vi1 == ui) v1 = -3e38f;
    }
    int ptn = (int)fmaxf(ptsum, 1.0f);   // trunc toward zero, in [1,10]

    // top-10 smallest (cost, idx): stable-argsort-equivalent selection
    int mysel = -1;
#pragma unroll
    for (int r = 0; r < KTOP; ++r) {
        float v = c0; int i = i0;
        if (c1 < v || (c1 == v && i1 < i)) { v = c1; i = i1; }
        wave_argmin(v, i);
        if (t == r) mysel = i;
        if (i0 == i) c0 = 3e38f;
        if (i1 == i) c1 = 3e38f;
    }
    if (t < ptn) mask[(long)pair * HW + mysel] = 1;
}

// ---------------- K3: per-anchor reassignment + num_pts ----------------
__global__ void k3_assign(const unsigned char* __restrict__ best,
                          unsigned char* __restrict__ mask,
                          unsigned char* __restrict__ gtconf,
                          int* __restrict__ numpts,
                          int G, int HW) {
    __shared__ int red[TPB];
    int b = blockIdx.y;
    int a = blockIdx.x * TPB + threadIdx.x;
    int cntf = 0;
    if (a < HW) {
        int cnt = 0;
        for (int g = 0; g < G; ++g)
            cnt += mask[((long)(b * G + g)) * HW + a];
        if (cnt > 1) {
            unsigned int bits = 1u << best[(long)b * HW + a];
            for (int g = 0; g < G; ++g)
                mask[((long)(b * G + g)) * HW + a] = (unsigned char)((bits >> g) & 1u);
        }
        cntf = (cnt > 1) ? 1 : cnt;
        gtconf[(long)b * HW + a] = (unsigned char)(cntf > 0 ? 1 : 0);
    }
    red[threadIdx.x] = cntf;
    __syncthreads();
    for (int s = TPB / 2; s; s >>= 1) {
        if (threadIdx.x < s) red[threadIdx.x] += red[threadIdx.x + s];
        __syncthreads();
    }
    if (threadIdx.x == 0 && red[0] > 0) atomicAdd(&numpts[b], red[0]);
}

// ---------------- K4a: l0 (CIoU) + l1 (cls BCE) over masked pairs ----------------
__global__ void k4_pair(const float* __restrict__ pred_boxes,
                        const float* __restrict__ gt_boxes,
                        const float* __restrict__ ps,
                        const int*   __restrict__ labels,
                        const float* __restrict__ Se,
                        const unsigned char* __restrict__ mask,
                        const int* __restrict__ numpts,
                        float* __restrict__ out,
                        int G, int HW, int NC) {
    __shared__ float r0[TPB];
    __shared__ float r1[TPB];
    int tid = threadIdx.x;
    int pair = blockIdx.x;
    int b = pair / G;
    const unsigned char* mrow = mask + (long)pair * HW;
    const float4 gb = ((const float4*)gt_boxes)[pair];
    float gx1 = gb.x, gy1 = gb.y, gx2 = gb.z, gy2 = gb.w;
    float w2 = gx2 - gx1, h2 = gy2 - gy1 + 1e-9f;
    int lab = labels[pair];
    const float* pbb   = pred_boxes + (long)b * HW * 4;
    const float* psb   = ps + (long)b * HW * NC;
    const float* Serow = Se + (long)b * HW;
    float at2 = atanf(w2 / h2);
    float s0 = 0.f, s1 = 0.f;
    for (int a = tid; a < HW; a += TPB) {
        if (!mrow[a]) continue;
        float4 pb = ((const float4*)pbb)[a];
        float w1 = pb.z - pb.x, h1 = pb.w - pb.y + 1e-9f;
        float iw = fminf(pb.z, gx2) - fmaxf(pb.x, gx1);
        float ih = fminf(pb.w, gy2) - fmaxf(pb.y, gy1);
        float inter = fmaxf(iw, 0.f) * fmaxf(ih, 0.f);
        float uni = w1 * h1 + w2 * h2 - inter + 1e-9f;
        float iou = inter / uni;
        float cw = fmaxf(pb.z, gx2) - fminf(pb.x, gx1);
        float ch = fmaxf(pb.w, gy2) - fminf(pb.y, gy1);
        float c2 = cw * cw + ch * ch + 1e-9f;
        float dx = gx1 + gx2 - pb.x - pb.z;
        float dy = gy1 + gy2 - pb.y - pb.w;
        float d2 = (dx * dx + dy * dy) * 0.25f;
        float dat = at2 - atanf(w1 / h1);
        float v = 0.4052847345693511f * dat * dat;   // 4/pi^2
        float alpha = v / (v - iou + 1.0f);          // (1.0+1e-9) rounds to 1.0f
        float ciou = iou - (d2 / c2 + v * alpha);
        s0 += 1.0f - ciou;
        float pl = psb[(long)a * NC + lab];
        s1 += Serow[a] - logf(pl + 1e-7f) + logf(1.f - pl + 1e-7f);
    }
    r0[tid] = s0; r1[tid] = s1;
    __syncthreads();
    for (int s = TPB / 2; s; s >>= 1) {
        if (tid < s) { r0[tid] += r0[tid + s]; r1[tid] += r1[tid + s]; }
        __syncthreads();
    }
    if (tid == 0 && (r0[0] != 0.f || r1[0] != 0.f)) {
        float np = (float)numpts[b];
        atomicAdd(out + 0, r0[0] / np);
        atomicAdd(out + 1, r1[0] / np);
    }
}

// ---------------- K4b: l2 (objectness BCE) ----------------
__global__ void k4_conf(const float* __restrict__ pred_conf,
                        const unsigned char* __restrict__ gtconf,
                        const int* __restrict__ numpts,
                        float* __restrict__ out, int HW) {
    __shared__ float red[TPB];
    int b = blockIdx.y;
    int a = blockIdx.x * TPB + threadIdx.x;
    float v = 0.f;
    if (a < HW) {
        float pc = pred_conf[(long)b * HW + a];
        v = gtconf[(long)b * HW + a] ? -logf(pc + 1e-7f) : -logf(1.f - pc + 1e-7f);
    }
    red[threadIdx.x] = v;
    __syncthreads();
    for (int s = TPB / 2; s; s >>= 1) {
        if (threadIdx.x < s) red[threadIdx.x] += red[threadIdx.x + s];
        __syncthreads();
    }
    if (threadIdx.x == 0) atomicAdd(out + 2, red[0] / (float)numpts[b]);
}

extern "C" void kernel_launch(void* const* d_in, const int* in_sizes, int n_in,
                              void* d_out, int out_size, void* d_ws, size_t ws_size,
                              hipStream_t stream) {
    const float* pred_boxes = (const float*)d_in[0];
    const float* gt_boxes   = (const float*)d_in[1];
    const void*  mask_gt    = d_in[2];
    const float* ps         = (const float*)d_in[3];
    const float* pred_conf  = (const float*)d_in[4];
    const int*   gt_labels  = (const int*)d_in[5];
    const float* anchors    = (const float*)d_in[6];
    const float* strides    = (const float*)d_in[7];
    float* out = (float*)d_out;

    const int HW = in_sizes[7];               // stride_tensor: hw
    const int BS = in_sizes[4] / HW;          // pred_conf: bs*hw
    const int G  = in_sizes[5] / BS;          // gt_labels: bs*G
    const int NC = in_sizes[3] / (BS * HW);   // pred_scores: bs*hw*nc

    char* w = (char*)d_ws;
    float* S  = (float*)w;                    w += (size_t)BS * HW * 4;
    float* Se = (float*)w;                    w += (size_t)BS * HW * 4;
    float* cost = (float*)w;                  w += (size_t)BS * G * HW * 4;
    int* numpts = (int*)w;                    w += 256;
    unsigned char* mask   = (unsigned char*)w; w += (size_t)BS * G * HW;
    unsigned char* gtconf = (unsigned char*)w; w += (size_t)BS * HW;
    unsigned char* best   = (unsigned char*)w; w += (size_t)BS * HW;
    // candidate buffers: BS*G * NSEG * KTOP each
    size_t ncand = (size_t)BS * G * NSEG * KTOP;
    float* cand_c  = (float*)w;               w += ncand * 4;
    int*   cand_i  = (int*)w;                 w += ncand * 4;
    float* cand_v  = (float*)w;               w += ncand * 4;
    int*   cand_vi = (int*)w;                 w += ncand * 4;

    k0_init<<<1, 64, 0, stream>>>(out, numpts, BS);

    int rows = BS * HW;
    k1_scores<<<(rows + 3) / 4, TPB, 0, stream>>>(ps, S, Se, rows, NC);

    dim3 g2a((HW + TPB - 1) / TPB, BS);
    k2a_cost<<<g2a, TPB, 0, stream>>>(pred_boxes, gt_boxes, mask_gt, ps, gt_labels,
                                      anchors, strides, S, cost, mask, best, G, HW, NC);

    dim3 g2b1(BS * G, NSEG);
    k2b1_seg<<<g2b1, TPB, 0, stream>>>(pred_boxes, gt_boxes, mask_gt, anchors,
                                       strides, cost, cand_c, cand_i, cand_v,
                                       cand_vi, G, HW);

    k2b2_merge<<<BS * G, 64, 0, stream>>>(mask_gt, cand_c, cand_i, cand_v,
                                          cand_vi, mask, HW);

    dim3 g3((HW + TPB - 1) / TPB, BS);
    k3_assign<<<g3, TPB, 0, stream>>>(best, mask, gtconf, numpts, G, HW);

    k4_pair<<<BS * G, TPB, 0, stream>>>(pred_boxes, gt_boxes, ps, gt_labels, Se,
                                        mask, numpts, out, G, HW, NC);

    k4_conf<<<g3, TPB, 0, stream>>>(pred_conf, gtconf, numpts, out, HW);
}

// Round 10
// 214.056 us; speedup vs baseline: 1.2628x; 1.2628x over previous
//
#include <hip/hip_runtime.h>
#include <math.h>

#define TPB 256
#define KTOP 10
#define GMAX 32
#define NITER 33   // ceil(8400/256)

__device__ __forceinline__ bool read_maskgt(const void* p, int i) {
    const unsigned char* b = (const unsigned char*)p;
    // counts >= 8 so mask_gt[0][1] is always true: byte[1]!=0 <=> bool-byte layout.
    if (b[1] != 0) return b[i] != 0;
    // int32 (value 0/1) or float32 (bits of 0.0/1.0) both: nonzero word == true
    return ((const int*)p)[i] != 0;
}

// ---------------- K0: zero outputs + num_pts accumulators ----------------
__global__ void k0_init(float* out, int* numpts, int bs) {
    int t = threadIdx.x;
    if (t < 3) out[t] = 0.0f;
    if (t < bs) numpts[t] = 0;
}

// ---------------- K1: per-(b,a) class sums S, Se ----------------
__global__ void k1_scores(const float* __restrict__ ps, float* __restrict__ S,
                          float* __restrict__ Se, int rows, int NC) {
    int r = blockIdx.x * 4 + (threadIdx.x >> 6);
    int lane = threadIdx.x & 63;
    if (r >= rows) return;
    const float* row = ps + (long)r * NC;
    float s = 0.f, se = 0.f;
    for (int c = lane; c < NC; c += 64) {
        float p = row[c];
        s  += -fmaxf(logf(1.0f - p), -100.0f);
        se += -logf(1.0f - p + 1e-7f);
    }
    for (int off = 32; off; off >>= 1) {
        s  += __shfl_down(s, off);
        se += __shfl_down(se, off);
    }
    if (lane == 0) { S[r] = s; Se[r] = se; }
}

// ---------------- K2a: fused cost over all g per anchor (row-local gather) ----
__global__ void k2a_cost(const float* __restrict__ pred_boxes,
                         const float* __restrict__ gt_boxes,
                         const void*  mask_gt,
                         const float* __restrict__ ps,
                         const int*   __restrict__ labels,
                         const float* __restrict__ anchors,
                         const float* __restrict__ strides,
                         const float* __restrict__ S,
                         float* __restrict__ cost,
                         unsigned char* __restrict__ mask,
                         unsigned char* __restrict__ best,
                         int G, int HW, int NC) {
    __shared__ float4 s_gb[GMAX];
    __shared__ float  s_ctrx[GMAX], s_ctry[GMAX];
    __shared__ int    s_lab[GMAX];
    __shared__ int    s_val[GMAX];

    int b = blockIdx.y;
    int tid = threadIdx.x;
    if (tid < G) {
        int pr = b * G + tid;
        float4 gb = ((const float4*)gt_boxes)[pr];
        s_gb[tid] = gb;
        s_ctrx[tid] = (gb.x + gb.z) * 0.5f;
        s_ctry[tid] = (gb.y + gb.w) * 0.5f;
        s_lab[tid] = labels[pr];
        s_val[tid] = read_maskgt(mask_gt, pr) ? 1 : 0;
    }
    __syncthreads();

    int a = blockIdx.x * TPB + tid;
    if (a >= HW) return;

    const float4 pb = ((const float4*)(pred_boxes + (long)b * HW * 4))[a];
    float ax = anchors[2 * a], ay = anchors[2 * a + 1];
    float st = strides[a];
    float apx = (ax + 0.5f) * st, apy = (ay + 0.5f) * st;
    float dis = 2.5f * st;
    float Sa = S[(long)b * HW + a];
    float w1 = pb.z - pb.x, h1 = pb.w - pb.y + 1e-9f;
    float w1h1 = w1 * h1;
    const float* __restrict__ row = ps + ((long)b * HW + a) * NC;

    float bestc = 3.4e38f;
    int bestg = 0;

#pragma unroll
    for (int g = 0; g < GMAX; ++g) {
        if (g >= G) break;
        long oidx = ((long)(b * G + g)) * HW + a;
        float c;
        if (!s_val[g]) {
            c = 1e6f;
        } else {
            float pl = row[s_lab[g]];
            float4 gb = s_gb[g];
            float gx1 = gb.x, gy1 = gb.y, gx2 = gb.z, gy2 = gb.w;
            bool in_boxes = (apx - gx1 > 0.f) & (apy - gy1 > 0.f) &
                            (gx2 - apx > 0.f) & (gy2 - apy > 0.f);
            float ctrx = s_ctrx[g], ctry = s_ctry[g];
            bool in_centers = (apx - (ctrx - dis) > 0.f) & (apy - (ctry - dis) > 0.f) &
                              ((ctrx + dis) - apx > 0.f) & ((ctry + dis) - apy > 0.f);
            bool fg = in_boxes | in_centers;
            bool in_both = in_boxes & in_centers;

            float w2 = gx2 - gx1, h2 = gy2 - gy1 + 1e-9f;
            float iw = fminf(pb.z, gx2) - fmaxf(pb.x, gx1);
            float ih = fminf(pb.w, gy2) - fmaxf(pb.y, gy1);
            float inter = fmaxf(iw, 0.f) * fmaxf(ih, 0.f);
            float uni = w1h1 + w2 * h2 - inter + 1e-9f;
            float iou = inter / uni;
            float iou_cost = -logf(iou + 1e-7f);

            float nll0 = -fmaxf(logf(pl), -100.f);
            float nll1 = -fmaxf(logf(1.f - pl), -100.f);
            float cls = Sa + (fg ? (nll0 - nll1) : 0.f);
            c = cls + 3.f * iou_cost + (in_both ? 0.f : 100000.f);
        }
        cost[oidx] = c;
        mask[oidx] = 0;
        if (c < bestc) { bestc = c; bestg = g; }   // first occurrence wins
    }
    best[(long)b * HW + a] = (unsigned char)bestg;
}

// ---------------- radix-select: k-th smallest u32 key over block's 33/thread ----
// 4 levels x 8 bits. Histogram uses run-length aggregated LDS atomics (clustered
// keys -> ~1-3 atomics/thread). Wave-0 parallel prefix finds the bucket.
// Returns exact key and count of keys strictly below it (same on all threads).
__device__ __forceinline__ void radix_sel(const unsigned* keys, int kth,
                                          unsigned* s_hist, int* s_bin, int* s_cum,
                                          int tid, unsigned& outKey, int& outCnt) {
    unsigned pref = 0;
    int kk = kth, cnt = 0;
#pragma unroll
    for (int lvl = 0; lvl < 4; ++lvl) {
        const int sh = 24 - 8 * lvl;
        s_hist[tid] = 0u;
        __syncthreads();
        int curBin = -1; unsigned curCnt = 0u;
#pragma unroll
        for (int j = 0; j < NITER; ++j) {
            unsigned key = keys[j];
            bool par = (lvl == 0) || ((key >> (sh + 8)) == pref);
            if (par) {
                int d = (int)((key >> sh) & 255u);
                if (d == curBin) curCnt++;
                else {
                    if (curBin >= 0) atomicAdd(&s_hist[curBin], curCnt);
                    curBin = d; curCnt = 1u;
                }
            }
        }
        if (curBin >= 0) atomicAdd(&s_hist[curBin], curCnt);
        __syncthreads();
        if (tid < 64) {
            unsigned h0 = s_hist[4 * tid + 0], h1 = s_hist[4 * tid + 1];
            unsigned h2 = s_hist[4 * tid + 2], h3 = s_hist[4 * tid + 3];
            int tot = (int)(h0 + h1 + h2 + h3);
            int incl = tot;
            for (int off = 1; off < 64; off <<= 1) {
                int o = __shfl_up(incl, off);
                if (tid >= off) incl += o;
            }
            int ex = incl - tot;
            bool hit = (ex < kk) && (incl >= kk);
            unsigned long long bal = __ballot(hit);
            int src = __ffsll((unsigned long long)bal) - 1;
            if (tid == src) {
                int c = ex; int bsel = 4 * tid;
                if (c + (int)h0 < kk) { c += (int)h0; bsel++;
                    if (c + (int)h1 < kk) { c += (int)h1; bsel++;
                        if (c + (int)h2 < kk) { c += (int)h2; bsel++; } } }
                *s_bin = bsel; *s_cum = c;
            }
        }
        __syncthreads();
        int bin = *s_bin, c = *s_cum;
        kk -= c; cnt += c;
        pref = (pref << 8) | (unsigned)bin;
        __syncthreads();
    }
    outKey = pref; outCnt = cnt;
}

// ---------------- K2sel: per-pair exact top-k via radix select ----------------
// grid BS*G. pt_num = trunc(max(sum of 10 largest fg-iou, 1));
// mask = the pt_num smallest (cost, idx) in stable-argsort order.
__global__ void k2_sel(const float* __restrict__ pred_boxes,
                       const float* __restrict__ gt_boxes,
                       const void*  mask_gt,
                       const float* __restrict__ anchors,
                       const float* __restrict__ strides,
                       const float* __restrict__ cost,
                       unsigned char* __restrict__ mask,
                       int G, int HW) {
    __shared__ unsigned s_hist[256];
    __shared__ int s_bin, s_cum;
    __shared__ float s_red[256];
    __shared__ int s_ptn;
    __shared__ unsigned s_tie[256];
    __shared__ int s_tiecnt;

    int pair = blockIdx.x;
    if (!read_maskgt(mask_gt, pair)) return;   // mask row stays 0 (k2a zeroed)
    int b = pair / G;
    int tid = threadIdx.x;

    const float4 gb = ((const float4*)gt_boxes)[pair];
    const float gx1 = gb.x, gy1 = gb.y, gx2 = gb.z, gy2 = gb.w;
    const float ctrx = (gx1 + gx2) * 0.5f, ctry = (gy1 + gy2) * 0.5f;
    const float w2 = gx2 - gx1, h2 = gy2 - gy1 + 1e-9f;

    const float* pbb  = pred_boxes + (long)b * HW * 4;
    const float* crow = cost + (long)pair * HW;

    unsigned ck[NITER], ik[NITER];
#pragma unroll
    for (int j = 0; j < NITER; ++j) {
        int a = j * TPB + tid;
        unsigned ckey = 0xFFFFFFFFu, ikey = 0xFFFFFFFFu;
        if (a < HW) {
            float4 pb = ((const float4*)pbb)[a];
            float ax = anchors[2 * a], ay = anchors[2 * a + 1];
            float st = strides[a];
            float apx = (ax + 0.5f) * st, apy = (ay + 0.5f) * st;
            bool in_boxes = (apx - gx1 > 0.f) & (apy - gy1 > 0.f) &
                            (gx2 - apx > 0.f) & (gy2 - apy > 0.f);
            float dis = 2.5f * st;
            bool in_centers = (apx - (ctrx - dis) > 0.f) & (apy - (ctry - dis) > 0.f) &
                              ((ctrx + dis) - apx > 0.f) & ((ctry + dis) - apy > 0.f);
            bool fg = in_boxes | in_centers;

            float w1 = pb.z - pb.x, h1 = pb.w - pb.y + 1e-9f;
            float iw = fminf(pb.z, gx2) - fmaxf(pb.x, gx1);
            float ih = fminf(pb.w, gy2) - fmaxf(pb.y, gy1);
            float inter = fmaxf(iw, 0.f) * fmaxf(ih, 0.f);
            float uni = w1 * h1 + w2 * h2 - inter + 1e-9f;
            float iou = inter / uni;

            float c = crow[a];
            unsigned cb = __float_as_uint(c);
            ckey = cb ^ (((int)cb < 0) ? 0xFFFFFFFFu : 0x80000000u);  // asc for any sign
            // iou >= 0: desc key = ~bits. fg iou==0 and non-fg both -> 0xFFFFFFFF,
            // both contribute 0 to the sum (matches where(isfinite, v, 0)).
            ikey = fg ? ~__float_as_uint(iou) : 0xFFFFFFFFu;
        }
        ck[j] = ckey; ik[j] = ikey;
    }

    // ---- pt_num: 10th-largest fg iou (10th-smallest desc-key) ----
    unsigned K10; int cnt10;
    radix_sel(ik, KTOP, s_hist, &s_bin, &s_cum, tid, K10, cnt10);

    float ls = 0.f;
#pragma unroll
    for (int j = 0; j < NITER; ++j)
        if (ik[j] < K10) ls += __uint_as_float(~ik[j]);
    s_red[tid] = ls;
    __syncthreads();
    for (int s = 128; s; s >>= 1) {
        if (tid < s) s_red[tid] += s_red[tid + s];
        __syncthreads();
    }
    if (tid == 0) {
        // (10 - cnt10) copies of the threshold value = top_k tie semantics
        float tot = s_red[0] + (float)(KTOP - cnt10) * __uint_as_float(~K10);
        s_ptn = (int)fmaxf(tot, 1.0f);   // trunc toward zero, in [1,10]
    }
    __syncthreads();
    int ptn = s_ptn;

    // ---- mask: the ptn smallest (cost, idx) lexicographic ----
    unsigned Kc; int cntc;
    radix_sel(ck, ptn, s_hist, &s_bin, &s_cum, tid, Kc, cntc);
    int tneed = ptn - cntc;   // >= 1 slots taken at the threshold value

    if (tid == 0) s_tiecnt = 0;
    __syncthreads();
    unsigned char* mrow = mask + (long)pair * HW;
#pragma unroll
    for (int j = 0; j < NITER; ++j) {
        int a = j * TPB + tid;
        if (a < HW) {
            if (ck[j] < Kc) mrow[a] = 1;
            else if (ck[j] == Kc) {
                int p = atomicAdd(&s_tiecnt, 1);
                if (p < 256) s_tie[p] = (unsigned)a;
            }
        }
    }
    __syncthreads();
    int m = min(s_tiecnt, 256);
    if (tneed >= m) {
        for (int e = tid; e < m; e += TPB) mrow[s_tie[e]] = 1;
    } else if (tneed > 0) {
        // smallest-index tneed of the tie group (stable argsort tie-break)
        for (int e = tid; e < m; e += TPB) {
            unsigned my = s_tie[e];
            int r = 0;
            for (int q = 0; q < m; ++q) r += (s_tie[q] < my) ? 1 : 0;
            if (r < tneed) mrow[my] = 1;
        }
    }
}

// ---------------- K3: per-anchor reassignment + num_pts ----------------
__global__ void k3_assign(const unsigned char* __restrict__ best,
                          unsigned char* __restrict__ mask,
                          unsigned char* __restrict__ gtconf,
                          int* __restrict__ numpts,
                          int G, int HW) {
    __shared__ int red[TPB];
    int b = blockIdx.y;
    int a = blockIdx.x * TPB + threadIdx.x;
    int cntf = 0;
    if (a < HW) {
        int cnt = 0;
        for (int g = 0; g < G; ++g)
            cnt += mask[((long)(b * G + g)) * HW + a];
        if (cnt > 1) {
            unsigned int bits = 1u << best[(long)b * HW + a];
            for (int g = 0; g < G; ++g)
                mask[((long)(b * G + g)) * HW + a] = (unsigned char)((bits >> g) & 1u);
        }
        cntf = (cnt > 1) ? 1 : cnt;
        gtconf[(long)b * HW + a] = (unsigned char)(cntf > 0 ? 1 : 0);
    }
    red[threadIdx.x] = cntf;
    __syncthreads();
    for (int s = TPB / 2; s; s >>= 1) {
        if (threadIdx.x < s) red[threadIdx.x] += red[threadIdx.x + s];
        __syncthreads();
    }
    if (threadIdx.x == 0 && red[0] > 0) atomicAdd(&numpts[b], red[0]);
}

// ---------------- K4a: l0 (CIoU) + l1 (cls BCE) over masked pairs ----------------
__global__ void k4_pair(const float* __restrict__ pred_boxes,
                        const float* __restrict__ gt_boxes,
                        const float* __restrict__ ps,
                        const int*   __restrict__ labels,
                        const float* __restrict__ Se,
                        const unsigned char* __restrict__ mask,
                        const int* __restrict__ numpts,
                        float* __restrict__ out,
                        int G, int HW, int NC) {
    __shared__ float r0[TPB];
    __shared__ float r1[TPB];
    int tid = threadIdx.x;
    int pair = blockIdx.x;
    int b = pair / G;
    const unsigned char* mrow = mask + (long)pair * HW;
    const float4 gb = ((const float4*)gt_boxes)[pair];
    float gx1 = gb.x, gy1 = gb.y, gx2 = gb.z, gy2 = gb.w;
    float w2 = gx2 - gx1, h2 = gy2 - gy1 + 1e-9f;
    int lab = labels[pair];
    const float* pbb   = pred_boxes + (long)b * HW * 4;
    const float* psb   = ps + (long)b * HW * NC;
    const float* Serow = Se + (long)b * HW;
    float at2 = atanf(w2 / h2);
    float s0 = 0.f, s1 = 0.f;
    for (int a = tid; a < HW; a += TPB) {
        if (!mrow[a]) continue;
        float4 pb = ((const float4*)pbb)[a];
        float w1 = pb.z - pb.x, h1 = pb.w - pb.y + 1e-9f;
        float iw = fminf(pb.z, gx2) - fmaxf(pb.x, gx1);
        float ih = fminf(pb.w, gy2) - fmaxf(pb.y, gy1);
        float inter = fmaxf(iw, 0.f) * fmaxf(ih, 0.f);
        float uni = w1 * h1 + w2 * h2 - inter + 1e-9f;
        float iou = inter / uni;
        float cw = fmaxf(pb.z, gx2) - fminf(pb.x, gx1);
        float ch = fmaxf(pb.w, gy2) - fminf(pb.y, gy1);
        float c2 = cw * cw + ch * ch + 1e-9f;
        float dx = gx1 + gx2 - pb.x - pb.z;
        float dy = gy1 + gy2 - pb.y - pb.w;
        float d2 = (dx * dx + dy * dy) * 0.25f;
        float dat = at2 - atanf(w1 / h1);
        float v = 0.4052847345693511f * dat * dat;   // 4/pi^2
        float alpha = v / (v - iou + 1.0f);          // (1.0+1e-9) rounds to 1.0f
        float ciou = iou - (d2 / c2 + v * alpha);
        s0 += 1.0f - ciou;
        float pl = psb[(long)a * NC + lab];
        s1 += Serow[a] - logf(pl + 1e-7f) + logf(1.f - pl + 1e-7f);
    }
    r0[tid] = s0; r1[tid] = s1;
    __syncthreads();
    for (int s = TPB / 2; s; s >>= 1) {
        if (tid < s) { r0[tid] += r0[tid + s]; r1[tid] += r1[tid + s]; }
        __syncthreads();
    }
    if (tid == 0 && (r0[0] != 0.f || r1[0] != 0.f)) {
        float np = (float)numpts[b];
        atomicAdd(out + 0, r0[0] / np);
        atomicAdd(out + 1, r1[0] / np);
    }
}

// ---------------- K4b: l2 (objectness BCE) ----------------
__global__ void k4_conf(const float* __restrict__ pred_conf,
                        const unsigned char* __restrict__ gtconf,
                        const int* __restrict__ numpts,
                        float* __restrict__ out, int HW) {
    __shared__ float red[TPB];
    int b = blockIdx.y;
    int a = blockIdx.x * TPB + threadIdx.x;
    float v = 0.f;
    if (a < HW) {
        float pc = pred_conf[(long)b * HW + a];
        v = gtconf[(long)b * HW + a] ? -logf(pc + 1e-7f) : -logf(1.f - pc + 1e-7f);
    }
    red[threadIdx.x] = v;
    __syncthreads();
    for (int s = TPB / 2; s; s >>= 1) {
        if (threadIdx.x < s) red[threadIdx.x] += red[threadIdx.x + s];
        __syncthreads();
    }
    if (threadIdx.x == 0) atomicAdd(out + 2, red[0] / (float)numpts[b]);
}

extern "C" void kernel_launch(void* const* d_in, const int* in_sizes, int n_in,
                              void* d_out, int out_size, void* d_ws, size_t ws_size,
                              hipStream_t stream) {
    const float* pred_boxes = (const float*)d_in[0];
    const float* gt_boxes   = (const float*)d_in[1];
    const void*  mask_gt    = d_in[2];
    const float* ps         = (const float*)d_in[3];
    const float* pred_conf  = (const float*)d_in[4];
    const int*   gt_labels  = (const int*)d_in[5];
    const float* anchors    = (const float*)d_in[6];
    const float* strides    = (const float*)d_in[7];
    float* out = (float*)d_out;

    const int HW = in_sizes[7];               // stride_tensor: hw
    const int BS = in_sizes[4] / HW;          // pred_conf: bs*hw
    const int G  = in_sizes[5] / BS;          // gt_labels: bs*G
    const int NC = in_sizes[3] / (BS * HW);   // pred_scores: bs*hw*nc

    char* w = (char*)d_ws;
    float* S  = (float*)w;                    w += (size_t)BS * HW * 4;
    float* Se = (float*)w;                    w += (size_t)BS * HW * 4;
    float* cost = (float*)w;                  w += (size_t)BS * G * HW * 4;
    int* numpts = (int*)w;                    w += 256;
    unsigned char* mask   = (unsigned char*)w; w += (size_t)BS * G * HW;
    unsigned char* gtconf = (unsigned char*)w; w += (size_t)BS * HW;
    unsigned char* best   = (unsigned char*)w;

    k0_init<<<1, 64, 0, stream>>>(out, numpts, BS);

    int rows = BS * HW;
    k1_scores<<<(rows + 3) / 4, TPB, 0, stream>>>(ps, S, Se, rows, NC);

    dim3 g2a((HW + TPB - 1) / TPB, BS);
    k2a_cost<<<g2a, TPB, 0, stream>>>(pred_boxes, gt_boxes, mask_gt, ps, gt_labels,
                                      anchors, strides, S, cost, mask, best, G, HW, NC);

    k2_sel<<<BS * G, TPB, 0, stream>>>(pred_boxes, gt_boxes, mask_gt, anchors,
                                       strides, cost, mask, G, HW);

    dim3 g3((HW + TPB - 1) / TPB, BS);
    k3_assign<<<g3, TPB, 0, stream>>>(best, mask, gtconf, numpts, G, HW);

    k4_pair<<<BS * G, TPB, 0, stream>>>(pred_boxes, gt_boxes, ps, gt_labels, Se,
                                        mask, numpts, out, G, HW, NC);

    k4_conf<<<g3, TPB, 0, stream>>>(pred_conf, gtconf, numpts, out, HW);
}

// Round 11
// 200.828 us; speedup vs baseline: 1.3460x; 1.0659x over previous
//
#include <hip/hip_runtime.h>
#include <math.h>

#define TPB 256
#define KTOP 10
#define GMAX 32
#define NITER 33   // ceil(8400/256)

__device__ __forceinline__ bool read_maskgt(const void* p, int i) {
    const unsigned char* b = (const unsigned char*)p;
    // counts >= 8 so mask_gt[0][1] is always true: byte[1]!=0 <=> bool-byte layout.
    if (b[1] != 0) return b[i] != 0;
    // int32 (value 0/1) or float32 (bits of 0.0/1.0) both: nonzero word == true
    return ((const int*)p)[i] != 0;
}

// ---------------- K0: zero outputs + per-batch accumulators ----------------
__global__ void k0_init(float* out, int* numpts, float* bce_sum, int bs) {
    int t = threadIdx.x;
    if (t < 3) out[t] = 0.0f;
    if (t < bs) { numpts[t] = 0; bce_sum[t] = 0.0f; }
}

// ---------------- K2a: fused row-sums (S,Se) + cost over all g per anchor ----
// Thread = one anchor. Streams its own 320B ps row (float4) to compute S/Se,
// which warms L1 so the 32 label gathers below are L1 hits.
__global__ void k2a_cost(const float* __restrict__ pred_boxes,
                         const float* __restrict__ gt_boxes,
                         const void*  mask_gt,
                         const float* __restrict__ ps,
                         const int*   __restrict__ labels,
                         const float* __restrict__ anchors,
                         const float* __restrict__ strides,
                         float* __restrict__ Se,
                         float* __restrict__ cost,
                         unsigned char* __restrict__ mask,
                         unsigned char* __restrict__ best,
                         int G, int HW, int NC) {
    __shared__ float4 s_gb[GMAX];
    __shared__ float  s_ctrx[GMAX], s_ctry[GMAX];
    __shared__ int    s_lab[GMAX];
    __shared__ int    s_val[GMAX];

    int b = blockIdx.y;
    int tid = threadIdx.x;
    if (tid < G) {
        int pr = b * G + tid;
        float4 gb = ((const float4*)gt_boxes)[pr];
        s_gb[tid] = gb;
        s_ctrx[tid] = (gb.x + gb.z) * 0.5f;
        s_ctry[tid] = (gb.y + gb.w) * 0.5f;
        s_lab[tid] = labels[pr];
        s_val[tid] = read_maskgt(mask_gt, pr) ? 1 : 0;
    }
    __syncthreads();

    int a = blockIdx.x * TPB + tid;
    if (a >= HW) return;

    // ---- fused k1: row sums S (local) and Se (stored), float4-vectorized ----
    const float* __restrict__ row = ps + ((long)b * HW + a) * NC;
    float Sa = 0.f, se = 0.f;
    int c = 0;
    for (; c + 4 <= NC; c += 4) {
        float4 v = *(const float4*)(row + c);
        Sa += -fmaxf(logf(1.0f - v.x), -100.0f) - fmaxf(logf(1.0f - v.y), -100.0f)
            - fmaxf(logf(1.0f - v.z), -100.0f) - fmaxf(logf(1.0f - v.w), -100.0f);
        se += -logf(1.0f - v.x + 1e-7f) - logf(1.0f - v.y + 1e-7f)
            - logf(1.0f - v.z + 1e-7f) - logf(1.0f - v.w + 1e-7f);
    }
    for (; c < NC; ++c) {
        float p = row[c];
        Sa += -fmaxf(logf(1.0f - p), -100.0f);
        se += -logf(1.0f - p + 1e-7f);
    }
    Se[(long)b * HW + a] = se;

    const float4 pb = ((const float4*)(pred_boxes + (long)b * HW * 4))[a];
    float ax = anchors[2 * a], ay = anchors[2 * a + 1];
    float st = strides[a];
    float apx = (ax + 0.5f) * st, apy = (ay + 0.5f) * st;
    float dis = 2.5f * st;
    float w1 = pb.z - pb.x, h1 = pb.w - pb.y + 1e-9f;
    float w1h1 = w1 * h1;

    float bestc = 3.4e38f;
    int bestg = 0;

#pragma unroll
    for (int g = 0; g < GMAX; ++g) {
        if (g >= G) break;
        long oidx = ((long)(b * G + g)) * HW + a;
        float cst;
        if (!s_val[g]) {
            cst = 1e6f;
        } else {
            float pl = row[s_lab[g]];   // L1-hot: row just streamed
            float4 gb = s_gb[g];
            float gx1 = gb.x, gy1 = gb.y, gx2 = gb.z, gy2 = gb.w;
            bool in_boxes = (apx - gx1 > 0.f) & (apy - gy1 > 0.f) &
                            (gx2 - apx > 0.f) & (gy2 - apy > 0.f);
            float ctrx = s_ctrx[g], ctry = s_ctry[g];
            bool in_centers = (apx - (ctrx - dis) > 0.f) & (apy - (ctry - dis) > 0.f) &
                              ((ctrx + dis) - apx > 0.f) & ((ctry + dis) - apy > 0.f);
            bool fg = in_boxes | in_centers;
            bool in_both = in_boxes & in_centers;

            float w2 = gx2 - gx1, h2 = gy2 - gy1 + 1e-9f;
            float iw = fminf(pb.z, gx2) - fmaxf(pb.x, gx1);
            float ih = fminf(pb.w, gy2) - fmaxf(pb.y, gy1);
            float inter = fmaxf(iw, 0.f) * fmaxf(ih, 0.f);
            float uni = w1h1 + w2 * h2 - inter + 1e-9f;
            float iou = inter / uni;
            float iou_cost = -logf(iou + 1e-7f);

            float nll0 = -fmaxf(logf(pl), -100.f);
            float nll1 = -fmaxf(logf(1.f - pl), -100.f);
            float cls = Sa + (fg ? (nll0 - nll1) : 0.f);
            cst = cls + 3.f * iou_cost + (in_both ? 0.f : 100000.f);
        }
        cost[oidx] = cst;
        mask[oidx] = 0;
        if (cst < bestc) { bestc = cst; bestg = g; }   // first occurrence wins
    }
    best[(long)b * HW + a] = (unsigned char)bestg;
}

// ---------------- radix-select: k-th smallest u32 key over block's 33/thread ----
// 4 levels x 8 bits. Histogram uses run-length aggregated LDS atomics (clustered
// keys -> ~1-3 atomics/thread). Wave-0 parallel prefix finds the bucket.
// Returns exact key and count of keys strictly below it (same on all threads).
__device__ __forceinline__ void radix_sel(const unsigned* keys, int kth,
                                          unsigned* s_hist, int* s_bin, int* s_cum,
                                          int tid, unsigned& outKey, int& outCnt) {
    unsigned pref = 0;
    int kk = kth, cnt = 0;
#pragma unroll
    for (int lvl = 0; lvl < 4; ++lvl) {
        const int sh = 24 - 8 * lvl;
        s_hist[tid] = 0u;
        __syncthreads();
        int curBin = -1; unsigned curCnt = 0u;
#pragma unroll
        for (int j = 0; j < NITER; ++j) {
            unsigned key = keys[j];
            bool par = (lvl == 0) || ((key >> (sh + 8)) == pref);
            if (par) {
                int d = (int)((key >> sh) & 255u);
                if (d == curBin) curCnt++;
                else {
                    if (curBin >= 0) atomicAdd(&s_hist[curBin], curCnt);
                    curBin = d; curCnt = 1u;
                }
            }
        }
        if (curBin >= 0) atomicAdd(&s_hist[curBin], curCnt);
        __syncthreads();
        if (tid < 64) {
            unsigned h0 = s_hist[4 * tid + 0], h1 = s_hist[4 * tid + 1];
            unsigned h2 = s_hist[4 * tid + 2], h3 = s_hist[4 * tid + 3];
            int tot = (int)(h0 + h1 + h2 + h3);
            int incl = tot;
            for (int off = 1; off < 64; off <<= 1) {
                int o = __shfl_up(incl, off);
                if (tid >= off) incl += o;
            }
            int ex = incl - tot;
            bool hit = (ex < kk) && (incl >= kk);
            unsigned long long bal = __ballot(hit);
            int src = __ffsll((unsigned long long)bal) - 1;
            if (tid == src) {
                int c = ex; int bsel = 4 * tid;
                if (c + (int)h0 < kk) { c += (int)h0; bsel++;
                    if (c + (int)h1 < kk) { c += (int)h1; bsel++;
                        if (c + (int)h2 < kk) { c += (int)h2; bsel++; } } }
                *s_bin = bsel; *s_cum = c;
            }
        }
        __syncthreads();
        int bin = *s_bin, c = *s_cum;
        kk -= c; cnt += c;
        pref = (pref << 8) | (unsigned)bin;
        __syncthreads();
    }
    outKey = pref; outCnt = cnt;
}

// ---------------- K2sel: per-pair exact top-k via radix select ----------------
// grid BS*G. pt_num = trunc(max(sum of 10 largest fg-iou, 1));
// mask = the pt_num smallest (cost, idx) in stable-argsort order.
__global__ void k2_sel(const float* __restrict__ pred_boxes,
                       const float* __restrict__ gt_boxes,
                       const void*  mask_gt,
                       const float* __restrict__ anchors,
                       const float* __restrict__ strides,
                       const float* __restrict__ cost,
                       unsigned char* __restrict__ mask,
                       int G, int HW) {
    __shared__ unsigned s_hist[256];
    __shared__ int s_bin, s_cum;
    __shared__ float s_red[256];
    __shared__ int s_ptn;
    __shared__ unsigned s_tie[256];
    __shared__ int s_tiecnt;

    int pair = blockIdx.x;
    if (!read_maskgt(mask_gt, pair)) return;   // mask row stays 0 (k2a zeroed)
    int b = pair / G;
    int tid = threadIdx.x;

    const float4 gb = ((const float4*)gt_boxes)[pair];
    const float gx1 = gb.x, gy1 = gb.y, gx2 = gb.z, gy2 = gb.w;
    const float ctrx = (gx1 + gx2) * 0.5f, ctry = (gy1 + gy2) * 0.5f;
    const float w2 = gx2 - gx1, h2 = gy2 - gy1 + 1e-9f;

    const float* pbb  = pred_boxes + (long)b * HW * 4;
    const float* crow = cost + (long)pair * HW;

    unsigned ck[NITER], ik[NITER];
#pragma unroll
    for (int j = 0; j < NITER; ++j) {
        int a = j * TPB + tid;
        unsigned ckey = 0xFFFFFFFFu, ikey = 0xFFFFFFFFu;
        if (a < HW) {
            float4 pb = ((const float4*)pbb)[a];
            float ax = anchors[2 * a], ay = anchors[2 * a + 1];
            float st = strides[a];
            float apx = (ax + 0.5f) * st, apy = (ay + 0.5f) * st;
            bool in_boxes = (apx - gx1 > 0.f) & (apy - gy1 > 0.f) &
                            (gx2 - apx > 0.f) & (gy2 - apy > 0.f);
            float dis = 2.5f * st;
            bool in_centers = (apx - (ctrx - dis) > 0.f) & (apy - (ctry - dis) > 0.f) &
                              ((ctrx + dis) - apx > 0.f) & ((ctry + dis) - apy > 0.f);
            bool fg = in_boxes | in_centers;

            float w1 = pb.z - pb.x, h1 = pb.w - pb.y + 1e-9f;
            float iw = fminf(pb.z, gx2) - fmaxf(pb.x, gx1);
            float ih = fminf(pb.w, gy2) - fmaxf(pb.y, gy1);
            float inter = fmaxf(iw, 0.f) * fmaxf(ih, 0.f);
            float uni = w1 * h1 + w2 * h2 - inter + 1e-9f;
            float iou = inter / uni;

            float c = crow[a];
            unsigned cb = __float_as_uint(c);
            ckey = cb ^ (((int)cb < 0) ? 0xFFFFFFFFu : 0x80000000u);  // asc for any sign
            // iou >= 0: desc key = ~bits. fg iou==0 and non-fg both -> 0xFFFFFFFF,
            // both contribute 0 to the sum (matches where(isfinite, v, 0)).
            ikey = fg ? ~__float_as_uint(iou) : 0xFFFFFFFFu;
        }
        ck[j] = ckey; ik[j] = ikey;
    }

    // ---- pt_num: 10th-largest fg iou (10th-smallest desc-key) ----
    unsigned K10; int cnt10;
    radix_sel(ik, KTOP, s_hist, &s_bin, &s_cum, tid, K10, cnt10);

    float ls = 0.f;
#pragma unroll
    for (int j = 0; j < NITER; ++j)
        if (ik[j] < K10) ls += __uint_as_float(~ik[j]);
    s_red[tid] = ls;
    __syncthreads();
    for (int s = 128; s; s >>= 1) {
        if (tid < s) s_red[tid] += s_red[tid + s];
        __syncthreads();
    }
    if (tid == 0) {
        // (10 - cnt10) copies of the threshold value = top_k tie semantics
        float tot = s_red[0] + (float)(KTOP - cnt10) * __uint_as_float(~K10);
        s_ptn = (int)fmaxf(tot, 1.0f);   // trunc toward zero, in [1,10]
    }
    __syncthreads();
    int ptn = s_ptn;

    // ---- mask: the ptn smallest (cost, idx) lexicographic ----
    unsigned Kc; int cntc;
    radix_sel(ck, ptn, s_hist, &s_bin, &s_cum, tid, Kc, cntc);
    int tneed = ptn - cntc;   // >= 1 slots taken at the threshold value

    if (tid == 0) s_tiecnt = 0;
    __syncthreads();
    unsigned char* mrow = mask + (long)pair * HW;
#pragma unroll
    for (int j = 0; j < NITER; ++j) {
        int a = j * TPB + tid;
        if (a < HW) {
            if (ck[j] < Kc) mrow[a] = 1;
            else if (ck[j] == Kc) {
                int p = atomicAdd(&s_tiecnt, 1);
                if (p < 256) s_tie[p] = (unsigned)a;
            }
        }
    }
    __syncthreads();
    int m = min(s_tiecnt, 256);
    if (tneed >= m) {
        for (int e = tid; e < m; e += TPB) mrow[s_tie[e]] = 1;
    } else if (tneed > 0) {
        // smallest-index tneed of the tie group (stable argsort tie-break)
        for (int e = tid; e < m; e += TPB) {
            unsigned my = s_tie[e];
            int r = 0;
            for (int q = 0; q < m; ++q) r += (s_tie[q] < my) ? 1 : 0;
            if (r < tneed) mrow[my] = 1;
        }
    }
}

// ---------------- K3: reassignment + num_pts + fused objectness BCE sum ----
__global__ void k3_assign(const unsigned char* __restrict__ best,
                          const float* __restrict__ pred_conf,
                          unsigned char* __restrict__ mask,
                          int* __restrict__ numpts,
                          float* __restrict__ bce_sum,
                          int G, int HW) {
    __shared__ int   red[TPB];
    __shared__ float redf[TPB];
    int b = blockIdx.y;
    int a = blockIdx.x * TPB + threadIdx.x;
    int cntf = 0;
    float vbce = 0.f;
    if (a < HW) {
        int cnt = 0;
        for (int g = 0; g < G; ++g)
            cnt += mask[((long)(b * G + g)) * HW + a];
        if (cnt > 1) {
            unsigned int bits = 1u << best[(long)b * HW + a];
            for (int g = 0; g < G; ++g)
                mask[((long)(b * G + g)) * HW + a] = (unsigned char)((bits >> g) & 1u);
        }
        cntf = (cnt > 1) ? 1 : cnt;
        float pc = pred_conf[(long)b * HW + a];
        vbce = (cntf > 0) ? -logf(pc + 1e-7f) : -logf(1.f - pc + 1e-7f);
    }
    red[threadIdx.x] = cntf;
    redf[threadIdx.x] = vbce;
    __syncthreads();
    for (int s = TPB / 2; s; s >>= 1) {
        if (threadIdx.x < s) {
            red[threadIdx.x]  += red[threadIdx.x + s];
            redf[threadIdx.x] += redf[threadIdx.x + s];
        }
        __syncthreads();
    }
    if (threadIdx.x == 0) {
        if (red[0] > 0) atomicAdd(&numpts[b], red[0]);
        atomicAdd(&bce_sum[b], redf[0]);
    }
}

// ---------------- K4: l0 (CIoU) + l1 (cls BCE) over masked pairs + l2 ----
__global__ void k4_pair(const float* __restrict__ pred_boxes,
                        const float* __restrict__ gt_boxes,
                        const float* __restrict__ ps,
                        const int*   __restrict__ labels,
                        const float* __restrict__ Se,
                        const unsigned char* __restrict__ mask,
                        const int* __restrict__ numpts,
                        const float* __restrict__ bce_sum,
                        float* __restrict__ out,
                        int G, int HW, int NC) {
    __shared__ float r0[TPB];
    __shared__ float r1[TPB];
    int tid = threadIdx.x;
    int pair = blockIdx.x;
    int b = pair / G;
    const unsigned char* mrow = mask + (long)pair * HW;
    const float4 gb = ((const float4*)gt_boxes)[pair];
    float gx1 = gb.x, gy1 = gb.y, gx2 = gb.z, gy2 = gb.w;
    float w2 = gx2 - gx1, h2 = gy2 - gy1 + 1e-9f;
    int lab = labels[pair];
    const float* pbb   = pred_boxes + (long)b * HW * 4;
    const float* psb   = ps + (long)b * HW * NC;
    const float* Serow = Se + (long)b * HW;
    float at2 = atanf(w2 / h2);
    float s0 = 0.f, s1 = 0.f;
    for (int a = tid; a < HW; a += TPB) {
        if (!mrow[a]) continue;
        float4 pb = ((const float4*)pbb)[a];
        float w1 = pb.z - pb.x, h1 = pb.w - pb.y + 1e-9f;
        float iw = fminf(pb.z, gx2) - fmaxf(pb.x, gx1);
        float ih = fminf(pb.w, gy2) - fmaxf(pb.y, gy1);
        float inter = fmaxf(iw, 0.f) * fmaxf(ih, 0.f);
        float uni = w1 * h1 + w2 * h2 - inter + 1e-9f;
        float iou = inter / uni;
        float cw = fmaxf(pb.z, gx2) - fminf(pb.x, gx1);
        float ch = fmaxf(pb.w, gy2) - fminf(pb.y, gy1);
        float c2 = cw * cw + ch * ch + 1e-9f;
        float dx = gx1 + gx2 - pb.x - pb.z;
        float dy = gy1 + gy2 - pb.y - pb.w;
        float d2 = (dx * dx + dy * dy) * 0.25f;
        float dat = at2 - atanf(w1 / h1);
        float v = 0.4052847345693511f * dat * dat;   // 4/pi^2
        float alpha = v / (v - iou + 1.0f);          // (1.0+1e-9) rounds to 1.0f
        float ciou = iou - (d2 / c2 + v * alpha);
        s0 += 1.0f - ciou;
        float pl = psb[(long)a * NC + lab];
        s1 += Serow[a] - logf(pl + 1e-7f) + logf(1.f - pl + 1e-7f);
    }
    r0[tid] = s0; r1[tid] = s1;
    __syncthreads();
    for (int s = TPB / 2; s; s >>= 1) {
        if (tid < s) { r0[tid] += r0[tid + s]; r1[tid] += r1[tid + s]; }
        __syncthreads();
    }
    if (tid == 0) {
        float np = (float)numpts[b];
        if (r0[0] != 0.f || r1[0] != 0.f) {
            atomicAdd(out + 0, r0[0] / np);
            atomicAdd(out + 1, r1[0] / np);
        }
        if ((pair % G) == 0)   // one block per batch adds l2
            atomicAdd(out + 2, bce_sum[b] / np);
    }
}

extern "C" void kernel_launch(void* const* d_in, const int* in_sizes, int n_in,
                              void* d_out, int out_size, void* d_ws, size_t ws_size,
                              hipStream_t stream) {
    const float* pred_boxes = (const float*)d_in[0];
    const float* gt_boxes   = (const float*)d_in[1];
    const void*  mask_gt    = d_in[2];
    const float* ps         = (const float*)d_in[3];
    const float* pred_conf  = (const float*)d_in[4];
    const int*   gt_labels  = (const int*)d_in[5];
    const float* anchors    = (const float*)d_in[6];
    const float* strides    = (const float*)d_in[7];
    float* out = (float*)d_out;

    const int HW = in_sizes[7];               // stride_tensor: hw
    const int BS = in_sizes[4] / HW;          // pred_conf: bs*hw
    const int G  = in_sizes[5] / BS;          // gt_labels: bs*G
    const int NC = in_sizes[3] / (BS * HW);   // pred_scores: bs*hw*nc

    char* w = (char*)d_ws;
    float* Se = (float*)w;                    w += (size_t)BS * HW * 4;
    float* cost = (float*)w;                  w += (size_t)BS * G * HW * 4;
    int* numpts = (int*)w;                    w += 256;
    float* bce_sum = (float*)w;               w += 256;
    unsigned char* mask = (unsigned char*)w;  w += (size_t)BS * G * HW;
    unsigned char* best = (unsigned char*)w;

    k0_init<<<1, 64, 0, stream>>>(out, numpts, bce_sum, BS);

    dim3 g2a((HW + TPB - 1) / TPB, BS);
    k2a_cost<<<g2a, TPB, 0, stream>>>(pred_boxes, gt_boxes, mask_gt, ps, gt_labels,
                                      anchors, strides, Se, cost, mask, best, G, HW, NC);

    k2_sel<<<BS * G, TPB, 0, stream>>>(pred_boxes, gt_boxes, mask_gt, anchors,
                                       strides, cost, mask, G, HW);

    dim3 g3((HW + TPB - 1) / TPB, BS);
    k3_assign<<<g3, TPB, 0, stream>>>(best, pred_conf, mask, numpts, bce_sum, G, HW);

    k4_pair<<<BS * G, TPB, 0, stream>>>(pred_boxes, gt_boxes, ps, gt_labels, Se,
                                        mask, numpts, bce_sum, out, G, HW, NC);
}

// Round 12
// 196.457 us; speedup vs baseline: 1.3759x; 1.0223x over previous
//
#include <hip/hip_runtime.h>
#include <math.h>

#define TPB 256
#define KTOP 10
#define GMAX 32
#define NITER 33   // ceil(8400/256)

__device__ __forceinline__ bool read_maskgt(const void* p, int i) {
    const unsigned char* b = (const unsigned char*)p;
    // counts >= 8 so mask_gt[0][1] is always true: byte[1]!=0 <=> bool-byte layout.
    if (b[1] != 0) return b[i] != 0;
    // int32 (value 0/1) or float32 (bits of 0.0/1.0) both: nonzero word == true
    return ((const int*)p)[i] != 0;
}

// ---------------- K0: zero outputs + per-batch accumulators ----------------
__global__ void k0_init(float* out, int* numpts, float* bce_sum, int bs) {
    int t = threadIdx.x;
    if (t < 3) out[t] = 0.0f;
    if (t < bs) { numpts[t] = 0; bce_sum[t] = 0.0f; }
}

// ---------------- K2a: 4 lanes per anchor; fused S/Se + cost over all g ----
// Quad lane q streams classes [20q, 20q+20) (5 float4), shfl_xor-combines
// S/Se across the quad, then handles gts g = q + 4*gi (gi=0..7).
// 537600 threads -> ~33 waves/CU capacity (vs 8 before).
__global__ void k2a_cost(const float* __restrict__ pred_boxes,
                         const float* __restrict__ gt_boxes,
                         const void*  mask_gt,
                         const float* __restrict__ ps,
                         const int*   __restrict__ labels,
                         const float* __restrict__ anchors,
                         const float* __restrict__ strides,
                         float* __restrict__ Se,
                         float* __restrict__ cost,
                         unsigned char* __restrict__ mask,
                         unsigned char* __restrict__ best,
                         int G, int HW, int NC) {
    __shared__ float4 s_gb[GMAX];
    __shared__ float  s_ctrx[GMAX], s_ctry[GMAX];
    __shared__ int    s_lab[GMAX];
    __shared__ int    s_val[GMAX];

    int b = blockIdx.y;
    int tid = threadIdx.x;
    if (tid < G) {
        int pr = b * G + tid;
        float4 gb = ((const float4*)gt_boxes)[pr];
        s_gb[tid] = gb;
        s_ctrx[tid] = (gb.x + gb.z) * 0.5f;
        s_ctry[tid] = (gb.y + gb.w) * 0.5f;
        s_lab[tid] = labels[pr];
        s_val[tid] = read_maskgt(mask_gt, pr) ? 1 : 0;
    }
    __syncthreads();

    int q = tid & 3;                       // lane within quad
    int a = blockIdx.x * (TPB / 4) + (tid >> 2);
    if (a >= HW) return;                   // uniform per quad

    // ---- fused row sums: lane q covers classes [20q, 20q+20) ----
    const float* __restrict__ row = ps + ((long)b * HW + a) * NC;
    int nper = NC / 4;                     // 20 for NC=80
    int c0 = q * nper;
    float Sa = 0.f, se = 0.f;
    int c = c0;
    for (; c + 4 <= c0 + nper; c += 4) {
        float4 v = *(const float4*)(row + c);
        Sa += -fmaxf(logf(1.0f - v.x), -100.0f) - fmaxf(logf(1.0f - v.y), -100.0f)
            - fmaxf(logf(1.0f - v.z), -100.0f) - fmaxf(logf(1.0f - v.w), -100.0f);
        se += -logf(1.0f - v.x + 1e-7f) - logf(1.0f - v.y + 1e-7f)
            - logf(1.0f - v.z + 1e-7f) - logf(1.0f - v.w + 1e-7f);
    }
    for (; c < c0 + nper; ++c) {
        float p = row[c];
        Sa += -fmaxf(logf(1.0f - p), -100.0f);
        se += -logf(1.0f - p + 1e-7f);
    }
    // tail classes (NC not divisible by 4): lane 3 takes them
    if (q == 3) {
        for (int cc = 4 * nper; cc < NC; ++cc) {
            float p = row[cc];
            Sa += -fmaxf(logf(1.0f - p), -100.0f);
            se += -logf(1.0f - p + 1e-7f);
        }
    }
    // quad combine (lanes of a quad are adjacent: xor 1, 2)
    Sa += __shfl_xor(Sa, 1); se += __shfl_xor(se, 1);
    Sa += __shfl_xor(Sa, 2); se += __shfl_xor(se, 2);
    if (q == 0) Se[(long)b * HW + a] = se;

    const float4 pb = ((const float4*)(pred_boxes + (long)b * HW * 4))[a];
    float ax = anchors[2 * a], ay = anchors[2 * a + 1];
    float st = strides[a];
    float apx = (ax + 0.5f) * st, apy = (ay + 0.5f) * st;
    float dis = 2.5f * st;
    float w1 = pb.z - pb.x, h1 = pb.w - pb.y + 1e-9f;
    float w1h1 = w1 * h1;

    float bestc = 3.4e38f;
    int bestg = 0x7fffffff;

#pragma unroll
    for (int gi = 0; gi < GMAX / 4; ++gi) {
        int g = q + 4 * gi;
        if (g >= G) break;
        long oidx = ((long)(b * G + g)) * HW + a;
        float cst;
        if (!s_val[g]) {
            cst = 1e6f;
        } else {
            float pl = row[s_lab[g]];   // L1-hot: row streamed by this quad
            float4 gb = s_gb[g];
            float gx1 = gb.x, gy1 = gb.y, gx2 = gb.z, gy2 = gb.w;
            bool in_boxes = (apx - gx1 > 0.f) & (apy - gy1 > 0.f) &
                            (gx2 - apx > 0.f) & (gy2 - apy > 0.f);
            float ctrx = s_ctrx[g], ctry = s_ctry[g];
            bool in_centers = (apx - (ctrx - dis) > 0.f) & (apy - (ctry - dis) > 0.f) &
                              ((ctrx + dis) - apx > 0.f) & ((ctry + dis) - apy > 0.f);
            bool fg = in_boxes | in_centers;
            bool in_both = in_boxes & in_centers;

            float w2 = gx2 - gx1, h2 = gy2 - gy1 + 1e-9f;
            float iw = fminf(pb.z, gx2) - fmaxf(pb.x, gx1);
            float ih = fminf(pb.w, gy2) - fmaxf(pb.y, gy1);
            float inter = fmaxf(iw, 0.f) * fmaxf(ih, 0.f);
            float uni = w1h1 + w2 * h2 - inter + 1e-9f;
            float iou = inter / uni;
            float iou_cost = -logf(iou + 1e-7f);

            float nll0 = -fmaxf(logf(pl), -100.f);
            float nll1 = -fmaxf(logf(1.f - pl), -100.f);
            float cls = Sa + (fg ? (nll0 - nll1) : 0.f);
            cst = cls + 3.f * iou_cost + (in_both ? 0.f : 100000.f);
        }
        cost[oidx] = cst;
        mask[oidx] = 0;
        // lexicographic (cost, g) min within this lane's disjoint g-set
        if (cst < bestc || (cst == bestc && g < bestg)) { bestc = cst; bestg = g; }
    }
    // quad combine: global argmin over g with first-occurrence (smallest g) ties
    {
        float oc = __shfl_xor(bestc, 1); int og = __shfl_xor(bestg, 1);
        if (oc < bestc || (oc == bestc && og < bestg)) { bestc = oc; bestg = og; }
        oc = __shfl_xor(bestc, 2); og = __shfl_xor(bestg, 2);
        if (oc < bestc || (oc == bestc && og < bestg)) { bestc = oc; bestg = og; }
    }
    if (q == 0) best[(long)b * HW + a] = (unsigned char)bestg;
}

// ---------------- radix-select: k-th smallest u32 key over block's 33/thread ----
// 4 levels x 8 bits. Histogram uses run-length aggregated LDS atomics (clustered
// keys -> ~1-3 atomics/thread). Wave-0 parallel prefix finds the bucket.
// Returns exact key and count of keys strictly below it (same on all threads).
__device__ __forceinline__ void radix_sel(const unsigned* keys, int kth,
                                          unsigned* s_hist, int* s_bin, int* s_cum,
                                          int tid, unsigned& outKey, int& outCnt) {
    unsigned pref = 0;
    int kk = kth, cnt = 0;
#pragma unroll
    for (int lvl = 0; lvl < 4; ++lvl) {
        const int sh = 24 - 8 * lvl;
        s_hist[tid] = 0u;
        __syncthreads();
        int curBin = -1; unsigned curCnt = 0u;
#pragma unroll
        for (int j = 0; j < NITER; ++j) {
            unsigned key = keys[j];
            bool par = (lvl == 0) || ((key >> (sh + 8)) == pref);
            if (par) {
                int d = (int)((key >> sh) & 255u);
                if (d == curBin) curCnt++;
                else {
                    if (curBin >= 0) atomicAdd(&s_hist[curBin], curCnt);
                    curBin = d; curCnt = 1u;
                }
            }
        }
        if (curBin >= 0) atomicAdd(&s_hist[curBin], curCnt);
        __syncthreads();
        if (tid < 64) {
            unsigned h0 = s_hist[4 * tid + 0], h1 = s_hist[4 * tid + 1];
            unsigned h2 = s_hist[4 * tid + 2], h3 = s_hist[4 * tid + 3];
            int tot = (int)(h0 + h1 + h2 + h3);
            int incl = tot;
            for (int off = 1; off < 64; off <<= 1) {
                int o = __shfl_up(incl, off);
                if (tid >= off) incl += o;
            }
            int ex = incl - tot;
            bool hit = (ex < kk) && (incl >= kk);
            unsigned long long bal = __ballot(hit);
            int src = __ffsll((unsigned long long)bal) - 1;
            if (tid == src) {
                int c = ex; int bsel = 4 * tid;
                if (c + (int)h0 < kk) { c += (int)h0; bsel++;
                    if (c + (int)h1 < kk) { c += (int)h1; bsel++;
                        if (c + (int)h2 < kk) { c += (int)h2; bsel++; } } }
                *s_bin = bsel; *s_cum = c;
            }
        }
        __syncthreads();
        int bin = *s_bin, c = *s_cum;
        kk -= c; cnt += c;
        pref = (pref << 8) | (unsigned)bin;
        __syncthreads();
    }
    outKey = pref; outCnt = cnt;
}

// ---------------- K2sel: per-pair exact top-k via radix select ----------------
// grid BS*G. pt_num = trunc(max(sum of 10 largest fg-iou, 1));
// mask = the pt_num smallest (cost, idx) in stable-argsort order.
__global__ void k2_sel(const float* __restrict__ pred_boxes,
                       const float* __restrict__ gt_boxes,
                       const void*  mask_gt,
                       const float* __restrict__ anchors,
                       const float* __restrict__ strides,
                       const float* __restrict__ cost,
                       unsigned char* __restrict__ mask,
                       int G, int HW) {
    __shared__ unsigned s_hist[256];
    __shared__ int s_bin, s_cum;
    __shared__ float s_red[256];
    __shared__ int s_ptn;
    __shared__ unsigned s_tie[256];
    __shared__ int s_tiecnt;

    int pair = blockIdx.x;
    if (!read_maskgt(mask_gt, pair)) return;   // mask row stays 0 (k2a zeroed)
    int b = pair / G;
    int tid = threadIdx.x;

    const float4 gb = ((const float4*)gt_boxes)[pair];
    const float gx1 = gb.x, gy1 = gb.y, gx2 = gb.z, gy2 = gb.w;
    const float ctrx = (gx1 + gx2) * 0.5f, ctry = (gy1 + gy2) * 0.5f;
    const float w2 = gx2 - gx1, h2 = gy2 - gy1 + 1e-9f;

    const float* pbb  = pred_boxes + (long)b * HW * 4;
    const float* crow = cost + (long)pair * HW;

    unsigned ck[NITER], ik[NITER];
#pragma unroll
    for (int j = 0; j < NITER; ++j) {
        int a = j * TPB + tid;
        unsigned ckey = 0xFFFFFFFFu, ikey = 0xFFFFFFFFu;
        if (a < HW) {
            float4 pb = ((const float4*)pbb)[a];
            float ax = anchors[2 * a], ay = anchors[2 * a + 1];
            float st = strides[a];
            float apx = (ax + 0.5f) * st, apy = (ay + 0.5f) * st;
            bool in_boxes = (apx - gx1 > 0.f) & (apy - gy1 > 0.f) &
                            (gx2 - apx > 0.f) & (gy2 - apy > 0.f);
            float dis = 2.5f * st;
            bool in_centers = (apx - (ctrx - dis) > 0.f) & (apy - (ctry - dis) > 0.f) &
                              ((ctrx + dis) - apx > 0.f) & ((ctry + dis) - apy > 0.f);
            bool fg = in_boxes | in_centers;

            float w1 = pb.z - pb.x, h1 = pb.w - pb.y + 1e-9f;
            float iw = fminf(pb.z, gx2) - fmaxf(pb.x, gx1);
            float ih = fminf(pb.w, gy2) - fmaxf(pb.y, gy1);
            float inter = fmaxf(iw, 0.f) * fmaxf(ih, 0.f);
            float uni = w1 * h1 + w2 * h2 - inter + 1e-9f;
            float iou = inter / uni;

            float c = crow[a];
            unsigned cb = __float_as_uint(c);
            ckey = cb ^ (((int)cb < 0) ? 0xFFFFFFFFu : 0x80000000u);  // asc for any sign
            // iou >= 0: desc key = ~bits. fg iou==0 and non-fg both -> 0xFFFFFFFF,
            // both contribute 0 to the sum (matches where(isfinite, v, 0)).
            ikey = fg ? ~__float_as_uint(iou) : 0xFFFFFFFFu;
        }
        ck[j] = ckey; ik[j] = ikey;
    }

    // ---- pt_num: 10th-largest fg iou (10th-smallest desc-key) ----
    unsigned K10; int cnt10;
    radix_sel(ik, KTOP, s_hist, &s_bin, &s_cum, tid, K10, cnt10);

    float ls = 0.f;
#pragma unroll
    for (int j = 0; j < NITER; ++j)
        if (ik[j] < K10) ls += __uint_as_float(~ik[j]);
    s_red[tid] = ls;
    __syncthreads();
    for (int s = 128; s; s >>= 1) {
        if (tid < s) s_red[tid] += s_red[tid + s];
        __syncthreads();
    }
    if (tid == 0) {
        // (10 - cnt10) copies of the threshold value = top_k tie semantics
        float tot = s_red[0] + (float)(KTOP - cnt10) * __uint_as_float(~K10);
        s_ptn = (int)fmaxf(tot, 1.0f);   // trunc toward zero, in [1,10]
    }
    __syncthreads();
    int ptn = s_ptn;

    // ---- mask: the ptn smallest (cost, idx) lexicographic ----
    unsigned Kc; int cntc;
    radix_sel(ck, ptn, s_hist, &s_bin, &s_cum, tid, Kc, cntc);
    int tneed = ptn - cntc;   // >= 1 slots taken at the threshold value

    if (tid == 0) s_tiecnt = 0;
    __syncthreads();
    unsigned char* mrow = mask + (long)pair * HW;
#pragma unroll
    for (int j = 0; j < NITER; ++j) {
        int a = j * TPB + tid;
        if (a < HW) {
            if (ck[j] < Kc) mrow[a] = 1;
            else if (ck[j] == Kc) {
                int p = atomicAdd(&s_tiecnt, 1);
                if (p < 256) s_tie[p] = (unsigned)a;
            }
        }
    }
    __syncthreads();
    int m = min(s_tiecnt, 256);
    if (tneed >= m) {
        for (int e = tid; e < m; e += TPB) mrow[s_tie[e]] = 1;
    } else if (tneed > 0) {
        // smallest-index tneed of the tie group (stable argsort tie-break)
        for (int e = tid; e < m; e += TPB) {
            unsigned my = s_tie[e];
            int r = 0;
            for (int q = 0; q < m; ++q) r += (s_tie[q] < my) ? 1 : 0;
            if (r < tneed) mrow[my] = 1;
        }
    }
}

// ---------------- K3: reassignment + num_pts + fused objectness BCE sum ----
__global__ void k3_assign(const unsigned char* __restrict__ best,
                          const float* __restrict__ pred_conf,
                          unsigned char* __restrict__ mask,
                          int* __restrict__ numpts,
                          float* __restrict__ bce_sum,
                          int G, int HW) {
    __shared__ int   red[TPB];
    __shared__ float redf[TPB];
    int b = blockIdx.y;
    int a = blockIdx.x * TPB + threadIdx.x;
    int cntf = 0;
    float vbce = 0.f;
    if (a < HW) {
        int cnt = 0;
        for (int g = 0; g < G; ++g)
            cnt += mask[((long)(b * G + g)) * HW + a];
        if (cnt > 1) {
            unsigned int bits = 1u << best[(long)b * HW + a];
            for (int g = 0; g < G; ++g)
                mask[((long)(b * G + g)) * HW + a] = (unsigned char)((bits >> g) & 1u);
        }
        cntf = (cnt > 1) ? 1 : cnt;
        float pc = pred_conf[(long)b * HW + a];
        vbce = (cntf > 0) ? -logf(pc + 1e-7f) : -logf(1.f - pc + 1e-7f);
    }
    red[threadIdx.x] = cntf;
    redf[threadIdx.x] = vbce;
    __syncthreads();
    for (int s = TPB / 2; s; s >>= 1) {
        if (threadIdx.x < s) {
            red[threadIdx.x]  += red[threadIdx.x + s];
            redf[threadIdx.x] += redf[threadIdx.x + s];
        }
        __syncthreads();
    }
    if (threadIdx.x == 0) {
        if (red[0] > 0) atomicAdd(&numpts[b], red[0]);
        atomicAdd(&bce_sum[b], redf[0]);
    }
}

// ---------------- K4: l0 (CIoU) + l1 (cls BCE) over masked pairs + l2 ----
__global__ void k4_pair(const float* __restrict__ pred_boxes,
                        const float* __restrict__ gt_boxes,
                        const float* __restrict__ ps,
                        const int*   __restrict__ labels,
                        const float* __restrict__ Se,
                        const unsigned char* __restrict__ mask,
                        const int* __restrict__ numpts,
                        const float* __restrict__ bce_sum,
                        float* __restrict__ out,
                        int G, int HW, int NC) {
    __shared__ float r0[TPB];
    __shared__ float r1[TPB];
    int tid = threadIdx.x;
    int pair = blockIdx.x;
    int b = pair / G;
    const unsigned char* mrow = mask + (long)pair * HW;
    const float4 gb = ((const float4*)gt_boxes)[pair];
    float gx1 = gb.x, gy1 = gb.y, gx2 = gb.z, gy2 = gb.w;
    float w2 = gx2 - gx1, h2 = gy2 - gy1 + 1e-9f;
    int lab = labels[pair];
    const float* pbb   = pred_boxes + (long)b * HW * 4;
    const float* psb   = ps + (long)b * HW * NC;
    const float* Serow = Se + (long)b * HW;
    float at2 = atanf(w2 / h2);
    float s0 = 0.f, s1 = 0.f;
    for (int a = tid; a < HW; a += TPB) {
        if (!mrow[a]) continue;
        float4 pb = ((const float4*)pbb)[a];
        float w1 = pb.z - pb.x, h1 = pb.w - pb.y + 1e-9f;
        float iw = fminf(pb.z, gx2) - fmaxf(pb.x, gx1);
        float ih = fminf(pb.w, gy2) - fmaxf(pb.y, gy1);
        float inter = fmaxf(iw, 0.f) * fmaxf(ih, 0.f);
        float uni = w1 * h1 + w2 * h2 - inter + 1e-9f;
        float iou = inter / uni;
        float cw = fmaxf(pb.z, gx2) - fminf(pb.x, gx1);
        float ch = fmaxf(pb.w, gy2) - fminf(pb.y, gy1);
        float c2 = cw * cw + ch * ch + 1e-9f;
        float dx = gx1 + gx2 - pb.x - pb.z;
        float dy = gy1 + gy2 - pb.y - pb.w;
        float d2 = (dx * dx + dy * dy) * 0.25f;
        float dat = at2 - atanf(w1 / h1);
        float v = 0.4052847345693511f * dat * dat;   // 4/pi^2
        float alpha = v / (v - iou + 1.0f);          // (1.0+1e-9) rounds to 1.0f
        float ciou = iou - (d2 / c2 + v * alpha);
        s0 += 1.0f - ciou;
        float pl = psb[(long)a * NC + lab];
        s1 += Serow[a] - logf(pl + 1e-7f) + logf(1.f - pl + 1e-7f);
    }
    r0[tid] = s0; r1[tid] = s1;
    __syncthreads();
    for (int s = TPB / 2; s; s >>= 1) {
        if (tid < s) { r0[tid] += r0[tid + s]; r1[tid] += r1[tid + s]; }
        __syncthreads();
    }
    if (tid == 0) {
        float np = (float)numpts[b];
        if (r0[0] != 0.f || r1[0] != 0.f) {
            atomicAdd(out + 0, r0[0] / np);
            atomicAdd(out + 1, r1[0] / np);
        }
        if ((pair % G) == 0)   // one block per batch adds l2
            atomicAdd(out + 2, bce_sum[b] / np);
    }
}

extern "C" void kernel_launch(void* const* d_in, const int* in_sizes, int n_in,
                              void* d_out, int out_size, void* d_ws, size_t ws_size,
                              hipStream_t stream) {
    const float* pred_boxes = (const float*)d_in[0];
    const float* gt_boxes   = (const float*)d_in[1];
    const void*  mask_gt    = d_in[2];
    const float* ps         = (const float*)d_in[3];
    const float* pred_conf  = (const float*)d_in[4];
    const int*   gt_labels  = (const int*)d_in[5];
    const float* anchors    = (const float*)d_in[6];
    const float* strides    = (const float*)d_in[7];
    float* out = (float*)d_out;

    const int HW = in_sizes[7];               // stride_tensor: hw
    const int BS = in_sizes[4] / HW;          // pred_conf: bs*hw
    const int G  = in_sizes[5] / BS;          // gt_labels: bs*G
    const int NC = in_sizes[3] / (BS * HW);   // pred_scores: bs*hw*nc

    char* w = (char*)d_ws;
    float* Se = (float*)w;                    w += (size_t)BS * HW * 4;
    float* cost = (float*)w;                  w += (size_t)BS * G * HW * 4;
    int* numpts = (int*)w;                    w += 256;
    float* bce_sum = (float*)w;               w += 256;
    unsigned char* mask = (unsigned char*)w;  w += (size_t)BS * G * HW;
    unsigned char* best = (unsigned char*)w;

    k0_init<<<1, 64, 0, stream>>>(out, numpts, bce_sum, BS);

    dim3 g2a((HW + TPB / 4 - 1) / (TPB / 4), BS);
    k2a_cost<<<g2a, TPB, 0, stream>>>(pred_boxes, gt_boxes, mask_gt, ps, gt_labels,
                                      anchors, strides, Se, cost, mask, best, G, HW, NC);

    k2_sel<<<BS * G, TPB, 0, stream>>>(pred_boxes, gt_boxes, mask_gt, anchors,
                                       strides, cost, mask, G, HW);

    dim3 g3((HW + TPB - 1) / TPB, BS);
    k3_assign<<<g3, TPB, 0, stream>>>(best, pred_conf, mask, numpts, bce_sum, G, HW);

    k4_pair<<<BS * G, TPB, 0, stream>>>(pred_boxes, gt_boxes, ps, gt_labels, Se,
                                        mask, numpts, bce_sum, out, G, HW, NC);
}

// Round 13
// 181.617 us; speedup vs baseline: 1.4883x; 1.0817x over previous
//
#include <hip/hip_runtime.h>
#include <math.h>

#define TPB 256
#define KTOP 10
#define GMAX 32
#define NITER 33   // ceil(8400/256)

__device__ __forceinline__ bool read_maskgt(const void* p, int i) {
    const unsigned char* b = (const unsigned char*)p;
    // counts >= 8 so mask_gt[0][1] is always true: byte[1]!=0 <=> bool-byte layout.
    if (b[1] != 0) return b[i] != 0;
    // int32 (value 0/1) or float32 (bits of 0.0/1.0) both: nonzero word == true
    return ((const int*)p)[i] != 0;
}

// ---------------- K0: zero outputs + per-batch accumulators ----------------
__global__ void k0_init(float* out, int* numpts, float* bce_sum, int bs) {
    int t = threadIdx.x;
    if (t < 3) out[t] = 0.0f;
    if (t < bs) { numpts[t] = 0; bce_sum[t] = 0.0f; }
}

// ---------------- K2a: 4 lanes per anchor; fused S/Se + cost over all g ----
// Quad streams the row INTERLEAVED: lane q reads float4 j = q+4i, so each
// instruction consumes one full 64B line (no cross-iteration line reuse ->
// no L1-eviction double-fetch). Quad shfl_xor-combines S/Se, then lane q
// handles gts g = q + 4*gi.
__global__ void k2a_cost(const float* __restrict__ pred_boxes,
                         const float* __restrict__ gt_boxes,
                         const void*  mask_gt,
                         const float* __restrict__ ps,
                         const int*   __restrict__ labels,
                         const float* __restrict__ anchors,
                         const float* __restrict__ strides,
                         float* __restrict__ Se,
                         float* __restrict__ cost,
                         unsigned char* __restrict__ best,
                         int G, int HW, int NC) {
    __shared__ float4 s_gb[GMAX];
    __shared__ float  s_ctrx[GMAX], s_ctry[GMAX];
    __shared__ int    s_lab[GMAX];
    __shared__ int    s_val[GMAX];

    int b = blockIdx.y;
    int tid = threadIdx.x;
    if (tid < G) {
        int pr = b * G + tid;
        float4 gb = ((const float4*)gt_boxes)[pr];
        s_gb[tid] = gb;
        s_ctrx[tid] = (gb.x + gb.z) * 0.5f;
        s_ctry[tid] = (gb.y + gb.w) * 0.5f;
        s_lab[tid] = labels[pr];
        s_val[tid] = read_maskgt(mask_gt, pr) ? 1 : 0;
    }
    __syncthreads();

    int q = tid & 3;                       // lane within quad
    int a = blockIdx.x * (TPB / 4) + (tid >> 2);
    if (a >= HW) return;                   // uniform per quad

    // ---- fused row sums, interleaved: lane q takes float4s q, q+4, q+8, ... ----
    const float* __restrict__ row = ps + ((long)b * HW + a) * NC;
    int nv4 = NC >> 2;
    float Sa = 0.f, se = 0.f;
    for (int j = q; j < nv4; j += 4) {
        float4 v = *(const float4*)(row + 4 * j);
        Sa += -fmaxf(logf(1.0f - v.x), -100.0f) - fmaxf(logf(1.0f - v.y), -100.0f)
            - fmaxf(logf(1.0f - v.z), -100.0f) - fmaxf(logf(1.0f - v.w), -100.0f);
        se += -logf(1.0f - v.x + 1e-7f) - logf(1.0f - v.y + 1e-7f)
            - logf(1.0f - v.z + 1e-7f) - logf(1.0f - v.w + 1e-7f);
    }
    if (q == 3) {                          // tail classes (NC % 4)
        for (int cc = nv4 * 4; cc < NC; ++cc) {
            float p = row[cc];
            Sa += -fmaxf(logf(1.0f - p), -100.0f);
            se += -logf(1.0f - p + 1e-7f);
        }
    }
    // quad combine (lanes of a quad are adjacent: xor 1, 2)
    Sa += __shfl_xor(Sa, 1); se += __shfl_xor(se, 1);
    Sa += __shfl_xor(Sa, 2); se += __shfl_xor(se, 2);
    if (q == 0) Se[(long)b * HW + a] = se;

    const float4 pb = ((const float4*)(pred_boxes + (long)b * HW * 4))[a];
    float ax = anchors[2 * a], ay = anchors[2 * a + 1];
    float st = strides[a];
    float apx = (ax + 0.5f) * st, apy = (ay + 0.5f) * st;
    float dis = 2.5f * st;
    float w1 = pb.z - pb.x, h1 = pb.w - pb.y + 1e-9f;
    float w1h1 = w1 * h1;

    float bestc = 3.4e38f;
    int bestg = 0x7fffffff;

#pragma unroll
    for (int gi = 0; gi < GMAX / 4; ++gi) {
        int g = q + 4 * gi;
        if (g >= G) break;
        long oidx = ((long)(b * G + g)) * HW + a;
        float cst;
        if (!s_val[g]) {
            cst = 1e6f;
        } else {
            float pl = row[s_lab[g]];   // L2-hot (row just streamed by this quad)
            float4 gb = s_gb[g];
            float gx1 = gb.x, gy1 = gb.y, gx2 = gb.z, gy2 = gb.w;
            bool in_boxes = (apx - gx1 > 0.f) & (apy - gy1 > 0.f) &
                            (gx2 - apx > 0.f) & (gy2 - apy > 0.f);
            float ctrx = s_ctrx[g], ctry = s_ctry[g];
            bool in_centers = (apx - (ctrx - dis) > 0.f) & (apy - (ctry - dis) > 0.f) &
                              ((ctrx + dis) - apx > 0.f) & ((ctry + dis) - apy > 0.f);
            bool fg = in_boxes | in_centers;
            bool in_both = in_boxes & in_centers;

            float w2 = gx2 - gx1, h2 = gy2 - gy1 + 1e-9f;
            float iw = fminf(pb.z, gx2) - fmaxf(pb.x, gx1);
            float ih = fminf(pb.w, gy2) - fmaxf(pb.y, gy1);
            float inter = fmaxf(iw, 0.f) * fmaxf(ih, 0.f);
            float uni = w1h1 + w2 * h2 - inter + 1e-9f;
            float iou = inter / uni;
            float iou_cost = -logf(iou + 1e-7f);

            float nll0 = -fmaxf(logf(pl), -100.f);
            float nll1 = -fmaxf(logf(1.f - pl), -100.f);
            float cls = Sa + (fg ? (nll0 - nll1) : 0.f);
            cst = cls + 3.f * iou_cost + (in_both ? 0.f : 100000.f);
        }
        cost[oidx] = cst;
        // lexicographic (cost, g) min within this lane's disjoint g-set
        if (cst < bestc || (cst == bestc && g < bestg)) { bestc = cst; bestg = g; }
    }
    // quad combine: global argmin over g with first-occurrence (smallest g) ties
    {
        float oc = __shfl_xor(bestc, 1); int og = __shfl_xor(bestg, 1);
        if (oc < bestc || (oc == bestc && og < bestg)) { bestc = oc; bestg = og; }
        oc = __shfl_xor(bestc, 2); og = __shfl_xor(bestg, 2);
        if (oc < bestc || (oc == bestc && og < bestg)) { bestc = oc; bestg = og; }
    }
    if (q == 0) best[(long)b * HW + a] = (unsigned char)bestg;
}

__device__ __forceinline__ void zero_row(unsigned char* mrow, int HW, int tid) {
    if ((HW & 15) == 0 && ((size_t)mrow & 15) == 0) {
        int nv = HW >> 4;
        int4 z = make_int4(0, 0, 0, 0);
        for (int j = tid; j < nv; j += TPB) ((int4*)mrow)[j] = z;
    } else {
        for (int a = tid; a < HW; a += TPB) mrow[a] = 0;
    }
}

// ---------------- radix-select: k-th smallest u32 key over block's 33/thread ----
// 4 levels x 8 bits. Histogram uses run-length aggregated LDS atomics (clustered
// keys -> ~1-3 atomics/thread). Wave-0 parallel prefix finds the bucket.
// Returns exact key and count of keys strictly below it (same on all threads).
__device__ __forceinline__ void radix_sel(const unsigned* keys, int kth,
                                          unsigned* s_hist, int* s_bin, int* s_cum,
                                          int tid, unsigned& outKey, int& outCnt) {
    unsigned pref = 0;
    int kk = kth, cnt = 0;
#pragma unroll
    for (int lvl = 0; lvl < 4; ++lvl) {
        const int sh = 24 - 8 * lvl;
        s_hist[tid] = 0u;
        __syncthreads();
        int curBin = -1; unsigned curCnt = 0u;
#pragma unroll
        for (int j = 0; j < NITER; ++j) {
            unsigned key = keys[j];
            bool par = (lvl == 0) || ((key >> (sh + 8)) == pref);
            if (par) {
                int d = (int)((key >> sh) & 255u);
                if (d == curBin) curCnt++;
                else {
                    if (curBin >= 0) atomicAdd(&s_hist[curBin], curCnt);
                    curBin = d; curCnt = 1u;
                }
            }
        }
        if (curBin >= 0) atomicAdd(&s_hist[curBin], curCnt);
        __syncthreads();
        if (tid < 64) {
            unsigned h0 = s_hist[4 * tid + 0], h1 = s_hist[4 * tid + 1];
            unsigned h2 = s_hist[4 * tid + 2], h3 = s_hist[4 * tid + 3];
            int tot = (int)(h0 + h1 + h2 + h3);
            int incl = tot;
            for (int off = 1; off < 64; off <<= 1) {
                int o = __shfl_up(incl, off);
                if (tid >= off) incl += o;
            }
            int ex = incl - tot;
            bool hit = (ex < kk) && (incl >= kk);
            unsigned long long bal = __ballot(hit);
            int src = __ffsll((unsigned long long)bal) - 1;
            if (tid == src) {
                int c = ex; int bsel = 4 * tid;
                if (c + (int)h0 < kk) { c += (int)h0; bsel++;
                    if (c + (int)h1 < kk) { c += (int)h1; bsel++;
                        if (c + (int)h2 < kk) { c += (int)h2; bsel++; } } }
                *s_bin = bsel; *s_cum = c;
            }
        }
        __syncthreads();
        int bin = *s_bin, c = *s_cum;
        kk -= c; cnt += c;
        pref = (pref << 8) | (unsigned)bin;
        __syncthreads();
    }
    outKey = pref; outCnt = cnt;
}

// ---------------- K2sel: per-pair exact top-k via radix select ----------------
// grid BS*G. Zeroes its mask row (coalesced), then:
// pt_num = trunc(max(sum of 10 largest fg-iou, 1));
// mask = the pt_num smallest (cost, idx) in stable-argsort order.
__global__ void k2_sel(const float* __restrict__ pred_boxes,
                       const float* __restrict__ gt_boxes,
                       const void*  mask_gt,
                       const float* __restrict__ anchors,
                       const float* __restrict__ strides,
                       const float* __restrict__ cost,
                       unsigned char* __restrict__ mask,
                       int G, int HW) {
    __shared__ unsigned s_hist[256];
    __shared__ int s_bin, s_cum;
    __shared__ float s_red[256];
    __shared__ int s_ptn;
    __shared__ unsigned s_tie[256];
    __shared__ int s_tiecnt;

    int pair = blockIdx.x;
    int tid = threadIdx.x;
    unsigned char* mrow = mask + (long)pair * HW;
    zero_row(mrow, HW, tid);               // barrier-ordered before 1-writes below
    if (!read_maskgt(mask_gt, pair)) return;
    int b = pair / G;

    const float4 gb = ((const float4*)gt_boxes)[pair];
    const float gx1 = gb.x, gy1 = gb.y, gx2 = gb.z, gy2 = gb.w;
    const float ctrx = (gx1 + gx2) * 0.5f, ctry = (gy1 + gy2) * 0.5f;
    const float w2 = gx2 - gx1, h2 = gy2 - gy1 + 1e-9f;

    const float* pbb  = pred_boxes + (long)b * HW * 4;
    const float* crow = cost + (long)pair * HW;

    unsigned ck[NITER], ik[NITER];
#pragma unroll
    for (int j = 0; j < NITER; ++j) {
        int a = j * TPB + tid;
        unsigned ckey = 0xFFFFFFFFu, ikey = 0xFFFFFFFFu;
        if (a < HW) {
            float4 pb = ((const float4*)pbb)[a];
            float ax = anchors[2 * a], ay = anchors[2 * a + 1];
            float st = strides[a];
            float apx = (ax + 0.5f) * st, apy = (ay + 0.5f) * st;
            bool in_boxes = (apx - gx1 > 0.f) & (apy - gy1 > 0.f) &
                            (gx2 - apx > 0.f) & (gy2 - apy > 0.f);
            float dis = 2.5f * st;
            bool in_centers = (apx - (ctrx - dis) > 0.f) & (apy - (ctry - dis) > 0.f) &
                              ((ctrx + dis) - apx > 0.f) & ((ctry + dis) - apy > 0.f);
            bool fg = in_boxes | in_centers;

            float w1 = pb.z - pb.x, h1 = pb.w - pb.y + 1e-9f;
            float iw = fminf(pb.z, gx2) - fmaxf(pb.x, gx1);
            float ih = fminf(pb.w, gy2) - fmaxf(pb.y, gy1);
            float inter = fmaxf(iw, 0.f) * fmaxf(ih, 0.f);
            float uni = w1 * h1 + w2 * h2 - inter + 1e-9f;
            float iou = inter / uni;

            float c = crow[a];
            unsigned cb = __float_as_uint(c);
            ckey = cb ^ (((int)cb < 0) ? 0xFFFFFFFFu : 0x80000000u);  // asc for any sign
            // iou >= 0: desc key = ~bits. fg iou==0 and non-fg both -> 0xFFFFFFFF,
            // both contribute 0 to the sum (matches where(isfinite, v, 0)).
            ikey = fg ? ~__float_as_uint(iou) : 0xFFFFFFFFu;
        }
        ck[j] = ckey; ik[j] = ikey;
    }

    // ---- pt_num: 10th-largest fg iou (10th-smallest desc-key) ----
    unsigned K10; int cnt10;
    radix_sel(ik, KTOP, s_hist, &s_bin, &s_cum, tid, K10, cnt10);

    float ls = 0.f;
#pragma unroll
    for (int j = 0; j < NITER; ++j)
        if (ik[j] < K10) ls += __uint_as_float(~ik[j]);
    s_red[tid] = ls;
    __syncthreads();
    for (int s = 128; s; s >>= 1) {
        if (tid < s) s_red[tid] += s_red[tid + s];
        __syncthreads();
    }
    if (tid == 0) {
        // (10 - cnt10) copies of the threshold value = top_k tie semantics
        float tot = s_red[0] + (float)(KTOP - cnt10) * __uint_as_float(~K10);
        s_ptn = (int)fmaxf(tot, 1.0f);   // trunc toward zero, in [1,10]
    }
    __syncthreads();
    int ptn = s_ptn;

    // ---- mask: the ptn smallest (cost, idx) lexicographic ----
    unsigned Kc; int cntc;
    radix_sel(ck, ptn, s_hist, &s_bin, &s_cum, tid, Kc, cntc);
    int tneed = ptn - cntc;   // >= 1 slots taken at the threshold value

    if (tid == 0) s_tiecnt = 0;
    __syncthreads();
#pragma unroll
    for (int j = 0; j < NITER; ++j) {
        int a = j * TPB + tid;
        if (a < HW) {
            if (ck[j] < Kc) mrow[a] = 1;
            else if (ck[j] == Kc) {
                int p = atomicAdd(&s_tiecnt, 1);
                if (p < 256) s_tie[p] = (unsigned)a;
            }
        }
    }
    __syncthreads();
    int m = min(s_tiecnt, 256);
    if (tneed >= m) {
        for (int e = tid; e < m; e += TPB) mrow[s_tie[e]] = 1;
    } else if (tneed > 0) {
        // smallest-index tneed of the tie group (stable argsort tie-break)
        for (int e = tid; e < m; e += TPB) {
            unsigned my = s_tie[e];
            int r = 0;
            for (int q = 0; q < m; ++q) r += (s_tie[q] < my) ? 1 : 0;
            if (r < tneed) mrow[my] = 1;
        }
    }
}

// ---------------- K3: reassignment + num_pts + fused objectness BCE sum ----
__global__ void k3_assign(const unsigned char* __restrict__ best,
                          const float* __restrict__ pred_conf,
                          unsigned char* __restrict__ mask,
                          int* __restrict__ numpts,
                          float* __restrict__ bce_sum,
                          int G, int HW) {
    __shared__ int   red[TPB];
    __shared__ float redf[TPB];
    int b = blockIdx.y;
    int a = blockIdx.x * TPB + threadIdx.x;
    int cntf = 0;
    float vbce = 0.f;
    if (a < HW) {
        int cnt = 0;
        for (int g = 0; g < G; ++g)
            cnt += mask[((long)(b * G + g)) * HW + a];
        if (cnt > 1) {
            unsigned int bits = 1u << best[(long)b * HW + a];
            for (int g = 0; g < G; ++g)
                mask[((long)(b * G + g)) * HW + a] = (unsigned char)((bits >> g) & 1u);
        }
        cntf = (cnt > 1) ? 1 : cnt;
        float pc = pred_conf[(long)b * HW + a];
        vbce = (cntf > 0) ? -logf(pc + 1e-7f) : -logf(1.f - pc + 1e-7f);
    }
    red[threadIdx.x] = cntf;
    redf[threadIdx.x] = vbce;
    __syncthreads();
    for (int s = TPB / 2; s; s >>= 1) {
        if (threadIdx.x < s) {
            red[threadIdx.x]  += red[threadIdx.x + s];
            redf[threadIdx.x] += redf[threadIdx.x + s];
        }
        __syncthreads();
    }
    if (threadIdx.x == 0) {
        if (red[0] > 0) atomicAdd(&numpts[b], red[0]);
        atomicAdd(&bce_sum[b], redf[0]);
    }
}

// ---------------- K4: l0 (CIoU) + l1 (cls BCE) over masked pairs + l2 ----
__global__ void k4_pair(const float* __restrict__ pred_boxes,
                        const float* __restrict__ gt_boxes,
                        const float* __restrict__ ps,
                        const int*   __restrict__ labels,
                        const float* __restrict__ Se,
                        const unsigned char* __restrict__ mask,
                        const int* __restrict__ numpts,
                        const float* __restrict__ bce_sum,
                        float* __restrict__ out,
                        int G, int HW, int NC) {
    __shared__ float r0[TPB];
    __shared__ float r1[TPB];
    int tid = threadIdx.x;
    int pair = blockIdx.x;
    int b = pair / G;
    const unsigned char* mrow = mask + (long)pair * HW;
    const float4 gb = ((const float4*)gt_boxes)[pair];
    float gx1 = gb.x, gy1 = gb.y, gx2 = gb.z, gy2 = gb.w;
    float w2 = gx2 - gx1, h2 = gy2 - gy1 + 1e-9f;
    int lab = labels[pair];
    const float* pbb   = pred_boxes + (long)b * HW * 4;
    const float* psb   = ps + (long)b * HW * NC;
    const float* Serow = Se + (long)b * HW;
    float at2 = atanf(w2 / h2);
    float s0 = 0.f, s1 = 0.f;
    for (int a = tid; a < HW; a += TPB) {
        if (!mrow[a]) continue;
        float4 pb = ((const float4*)pbb)[a];
        float w1 = pb.z - pb.x, h1 = pb.w - pb.y + 1e-9f;
        float iw = fminf(pb.z, gx2) - fmaxf(pb.x, gx1);
        float ih = fminf(pb.w, gy2) - fmaxf(pb.y, gy1);
        float inter = fmaxf(iw, 0.f) * fmaxf(ih, 0.f);
        float uni = w1 * h1 + w2 * h2 - inter + 1e-9f;
        float iou = inter / uni;
        float cw = fmaxf(pb.z, gx2) - fminf(pb.x, gx1);
        float ch = fmaxf(pb.w, gy2) - fminf(pb.y, gy1);
        float c2 = cw * cw + ch * ch + 1e-9f;
        float dx = gx1 + gx2 - pb.x - pb.z;
        float dy = gy1 + gy2 - pb.y - pb.w;
        float d2 = (dx * dx + dy * dy) * 0.25f;
        float dat = at2 - atanf(w1 / h1);
        float v = 0.4052847345693511f * dat * dat;   // 4/pi^2
        float alpha = v / (v - iou + 1.0f);          // (1.0+1e-9) rounds to 1.0f
        float ciou = iou - (d2 / c2 + v * alpha);
        s0 += 1.0f - ciou;
        float pl = psb[(long)a * NC + lab];
        s1 += Serow[a] - logf(pl + 1e-7f) + logf(1.f - pl + 1e-7f);
    }
    r0[tid] = s0; r1[tid] = s1;
    __syncthreads();
    for (int s = TPB / 2; s; s >>= 1) {
        if (tid < s) { r0[tid] += r0[tid + s]; r1[tid] += r1[tid + s]; }
        __syncthreads();
    }
    if (tid == 0) {
        float np = (float)numpts[b];
        if (r0[0] != 0.f || r1[0] != 0.f) {
            atomicAdd(out + 0, r0[0] / np);
            atomicAdd(out + 1, r1[0] / np);
        }
        if ((pair % G) == 0)   // one block per batch adds l2
            atomicAdd(out + 2, bce_sum[b] / np);
    }
}

extern "C" void kernel_launch(void* const* d_in, const int* in_sizes, int n_in,
                              void* d_out, int out_size, void* d_ws, size_t ws_size,
                              hipStream_t stream) {
    const float* pred_boxes = (const float*)d_in[0];
    const float* gt_boxes   = (const float*)d_in[1];
    const void*  mask_gt    = d_in[2];
    const float* ps         = (const float*)d_in[3];
    const float* pred_conf  = (const float*)d_in[4];
    const int*   gt_labels  = (const int*)d_in[5];
    const float* anchors    = (const float*)d_in[6];
    const float* strides    = (const float*)d_in[7];
    float* out = (float*)d_out;

    const int HW = in_sizes[7];               // stride_tensor: hw
    const int BS = in_sizes[4] / HW;          // pred_conf: bs*hw
    const int G  = in_sizes[5] / BS;          // gt_labels: bs*G
    const int NC = in_sizes[3] / (BS * HW);   // pred_scores: bs*hw*nc

    char* w = (char*)d_ws;
    float* Se = (float*)w;                    w += (size_t)BS * HW * 4;
    float* cost = (float*)w;                  w += (size_t)BS * G * HW * 4;
    int* numpts = (int*)w;                    w += 256;
    float* bce_sum = (float*)w;               w += 256;
    unsigned char* mask = (unsigned char*)w;  w += (size_t)BS * G * HW;
    unsigned char* best = (unsigned char*)w;

    k0_init<<<1, 64, 0, stream>>>(out, numpts, bce_sum, BS);

    dim3 g2a((HW + TPB / 4 - 1) / (TPB / 4), BS);
    k2a_cost<<<g2a, TPB, 0, stream>>>(pred_boxes, gt_boxes, mask_gt, ps, gt_labels,
                                      anchors, strides, Se, cost, best, G, HW, NC);

    k2_sel<<<BS * G, TPB, 0, stream>>>(pred_boxes, gt_boxes, mask_gt, anchors,
                                       strides, cost, mask, G, HW);

    dim3 g3((HW + TPB - 1) / TPB, BS);
    k3_assign<<<g3, TPB, 0, stream>>>(best, pred_conf, mask, numpts, bce_sum, G, HW);

    k4_pair<<<BS * G, TPB, 0, stream>>>(pred_boxes, gt_boxes, ps, gt_labels, Se,
                                        mask, numpts, bce_sum, out, G, HW, NC);
}